// Round 1
// baseline (1376.625 us; speedup 1.0000x reference)
//
#include <hip/hip_runtime.h>

#define L_ 256
#define C_ 256
#define H_ 8
#define D_ 32
#define F_ 512
#define M_ (L_*L_)   // 65536 rows

// ---------------- LayerNorm over last dim (C=256), one wave per row ----------
__global__ __launch_bounds__(256) void ln_k(const float* __restrict__ in,
    const float* __restrict__ g, const float* __restrict__ b,
    float* __restrict__ out) {
  int wid = threadIdx.x >> 6, lane = threadIdx.x & 63;
  size_t row = (size_t)blockIdx.x * 4 + wid;
  const float* x = in + row * C_;
  float4 v = *(const float4*)&x[lane*4];
  float s  = v.x + v.y + v.z + v.w;
  float s2 = v.x*v.x + v.y*v.y + v.z*v.z + v.w*v.w;
  #pragma unroll
  for (int off = 1; off < 64; off <<= 1) {
    s  += __shfl_xor(s,  off);
    s2 += __shfl_xor(s2, off);
  }
  float mean = s * (1.0f/C_);
  float var  = s2 * (1.0f/C_) - mean*mean;
  float inv  = rsqrtf(var + 1e-5f);
  float4 gg = *(const float4*)&g[lane*4];
  float4 bb = *(const float4*)&b[lane*4];
  float4 o;
  o.x = (v.x-mean)*inv*gg.x + bb.x;
  o.y = (v.y-mean)*inv*gg.y + bb.y;
  o.z = (v.z-mean)*inv*gg.z + bb.z;
  o.w = (v.w-mean)*inv*gg.w + bb.w;
  *(float4*)&out[row*C_ + lane*4] = o;
}

// ---------------- fp32 NT GEMM: O[m,n] = sum_k A[m,k]*W[n,k] + bias[n] -------
// optional ReLU, optional residual add R[m,n]. 128x128 tile, 8x8 per thread.
template<bool RELU, bool ADD>
__global__ __launch_bounds__(256) void gemm_nt(
    const float* __restrict__ A, const float* __restrict__ W,
    const float* __restrict__ bias, const float* __restrict__ R,
    float* __restrict__ O, int M, int N, int K) {
  __shared__ float As[16][132];   // [k][m], pad 132: 2-way write conflicts only
  __shared__ float Bs[16][132];   // [k][n]
  const int bm = blockIdx.x * 128;
  const int bn = blockIdx.y * 128;
  const int t  = threadIdx.x;
  const int tx = t & 15, ty = t >> 4;
  float acc[8][8];
  #pragma unroll
  for (int i = 0; i < 8; ++i)
    #pragma unroll
    for (int j = 0; j < 8; ++j) acc[i][j] = 0.f;

  for (int k0 = 0; k0 < K; k0 += 16) {
    #pragma unroll
    for (int l = 0; l < 2; ++l) {
      int idx = t + l*256;        // 0..511
      int r   = idx >> 2;         // 0..127
      int kq  = (idx & 3) * 4;    // 0,4,8,12
      float4 a4 = *(const float4*)&A[(size_t)(bm + r)*K + k0 + kq];
      As[kq+0][r] = a4.x; As[kq+1][r] = a4.y; As[kq+2][r] = a4.z; As[kq+3][r] = a4.w;
      float4 w4 = *(const float4*)&W[(size_t)(bn + r)*K + k0 + kq];
      Bs[kq+0][r] = w4.x; Bs[kq+1][r] = w4.y; Bs[kq+2][r] = w4.z; Bs[kq+3][r] = w4.w;
    }
    __syncthreads();
    #pragma unroll
    for (int kk = 0; kk < 16; ++kk) {
      float a[8], b[8];
      *(float4*)&a[0] = *(const float4*)&As[kk][ty*8];
      *(float4*)&a[4] = *(const float4*)&As[kk][ty*8+4];
      *(float4*)&b[0] = *(const float4*)&Bs[kk][tx*8];
      *(float4*)&b[4] = *(const float4*)&Bs[kk][tx*8+4];
      #pragma unroll
      for (int i = 0; i < 8; ++i)
        #pragma unroll
        for (int j = 0; j < 8; ++j)
          acc[i][j] += a[i]*b[j];
    }
    __syncthreads();
  }
  #pragma unroll
  for (int i = 0; i < 8; ++i) {
    size_t m = (size_t)bm + ty*8 + i;
    #pragma unroll
    for (int j4 = 0; j4 < 2; ++j4) {
      int n = bn + tx*8 + j4*4;
      float4 o;
      o.x = acc[i][j4*4+0] + bias[n+0];
      o.y = acc[i][j4*4+1] + bias[n+1];
      o.z = acc[i][j4*4+2] + bias[n+2];
      o.w = acc[i][j4*4+3] + bias[n+3];
      if (RELU) {
        o.x = fmaxf(o.x,0.f); o.y = fmaxf(o.y,0.f);
        o.z = fmaxf(o.z,0.f); o.w = fmaxf(o.w,0.f);
      }
      if (ADD) {
        float4 r4 = *(const float4*)&R[m*(size_t)N + n];
        o.x += r4.x; o.y += r4.y; o.z += r4.z; o.w += r4.w;
      }
      *(float4*)&O[m*(size_t)N + n] = o;
    }
  }
}

// ---------------- fused attention per (j,h): one thread per query row i -----
// scores[i,k] = q[i,j,h,:]·k[k,j,h,:] * SCALE + bias[h,i,k]; softmax over k;
// attn[i,j,h,:] = sum_k p * v[k,j,h,:]
__global__ __launch_bounds__(256) void attn_k(
    const float* __restrict__ q, const float* __restrict__ k,
    const float* __restrict__ v, const float* __restrict__ bias,
    const int* __restrict__ mask, float* __restrict__ attn) {
  __shared__ float Ks[256][32];   // broadcast reads -> no pad needed
  __shared__ float Vs[256][32];
  const int j = blockIdx.x >> 3;
  const int h = blockIdx.x & 7;
  const int i = threadIdx.x;
  const size_t rowoff = ((size_t)i*2048 + j*8 + h) * 32; // ((i*L+j)*H+h)*D
  float q_r[32];
  #pragma unroll
  for (int d = 0; d < 32; d += 4)
    *(float4*)&q_r[d] = *(const float4*)&q[rowoff + d];
  #pragma unroll
  for (int d = 0; d < 32; d += 4) {
    *(float4*)&Ks[i][d] = *(const float4*)&k[rowoff + d];
    *(float4*)&Vs[i][d] = *(const float4*)&v[rowoff + d];
  }
  __syncthreads();
  const float* brow = bias + ((size_t)h*256 + i)*256;
  const int*   mrow = mask + (size_t)i*256;
  float mx = -1e30f, l = 0.f;
  float acc[32];
  #pragma unroll
  for (int d = 0; d < 32; ++d) acc[d] = 0.f;
  for (int kc = 0; kc < 64; ++kc) {
    float4 b4 = *(const float4*)&brow[kc*4];
    int4  m4 = *(const int4*)&mrow[kc*4];
    float bv4[4] = {b4.x, b4.y, b4.z, b4.w};
    int   mv4[4] = {m4.x, m4.y, m4.z, m4.w};
    #pragma unroll
    for (int u = 0; u < 4; ++u) {
      int kk = kc*4 + u;
      float s = 0.f;
      #pragma unroll
      for (int d = 0; d < 32; d += 4) {
        float4 kv = *(const float4*)&Ks[kk][d];
        s += q_r[d]*kv.x + q_r[d+1]*kv.y + q_r[d+2]*kv.z + q_r[d+3]*kv.w;
      }
      s = s * 0.17677669529663687f + bv4[u];
      if (mv4[u] == 0) s = -1e30f;
      if (s > mx) {                      // rare rescale path
        float corr = __expf(mx - s);
        l *= corr;
        #pragma unroll
        for (int d = 0; d < 32; ++d) acc[d] *= corr;
        mx = s;
      }
      float p = __expf(s - mx);
      if (mv4[u] == 0) p = 0.f;
      l += p;
      #pragma unroll
      for (int d = 0; d < 32; d += 4) {
        float4 vv = *(const float4*)&Vs[kk][d];
        acc[d]   += p*vv.x;
        acc[d+1] += p*vv.y;
        acc[d+2] += p*vv.z;
        acc[d+3] += p*vv.w;
      }
    }
  }
  float invl = 1.0f / l;
  #pragma unroll
  for (int d = 0; d < 32; d += 4) {
    float4 o;
    o.x = acc[d]*invl; o.y = acc[d+1]*invl;
    o.z = acc[d+2]*invl; o.w = acc[d+3]*invl;
    *(float4*)&attn[rowoff + d] = o;
  }
}

extern "C" void kernel_launch(void* const* d_in, const int* in_sizes, int n_in,
                              void* d_out, int out_size, void* d_ws, size_t ws_size,
                              hipStream_t stream) {
  const float* pair_repr = (const float*)d_in[0];
  const float* pair_bias = (const float*)d_in[1];
  const float* Wq = (const float*)d_in[2];
  const float* bq = (const float*)d_in[3];
  const float* Wk = (const float*)d_in[4];
  const float* bk = (const float*)d_in[5];
  const float* Wv = (const float*)d_in[6];
  const float* bv = (const float*)d_in[7];
  const float* Wo = (const float*)d_in[8];
  const float* bo = (const float*)d_in[9];
  const float* W1 = (const float*)d_in[10];
  const float* b1 = (const float*)d_in[11];
  const float* W2 = (const float*)d_in[12];
  const float* b2 = (const float*)d_in[13];
  const float* g1 = (const float*)d_in[14];
  const float* be1= (const float*)d_in[15];
  const float* g2 = (const float*)d_in[16];
  const float* be2= (const float*)d_in[17];
  const int* mask = (const int*)d_in[18];
  float* out = (float*)d_out;

  const size_t S = (size_t)M_ * C_;     // 16.7M floats = 64MB
  float* ws = (float*)d_ws;
  float* qb = ws;                        // q; later attn-out; later y
  float* kb = ws + S;                    // k; later ff hidden (S..3S)
  float* vb = ws + 2*S;                  // v
  float* hb = ws + S;                    // ff hidden [M,512]

  // 1. x = LN1(pair_repr) -> d_out (scratch; fully rewritten later)
  ln_k<<<dim3(M_/4), 256, 0, stream>>>(pair_repr, g1, be1, out);
  // 2-4. q,k,v projections
  gemm_nt<false,false><<<dim3(M_/128, C_/128), 256, 0, stream>>>(out, Wq, bq, nullptr, qb, M_, C_, C_);
  gemm_nt<false,false><<<dim3(M_/128, C_/128), 256, 0, stream>>>(out, Wk, bk, nullptr, kb, M_, C_, C_);
  gemm_nt<false,false><<<dim3(M_/128, C_/128), 256, 0, stream>>>(out, Wv, bv, nullptr, vb, M_, C_, C_);
  // 5. attention -> qb (aliases q: per-thread own-row read-before-write, per-block disjoint slices)
  attn_k<<<dim3(L_*H_), 256, 0, stream>>>(qb, kb, vb, pair_bias, mask, qb);
  // 6. pr = attn@Wo.T + bo + pair_repr -> d_out
  gemm_nt<false,true><<<dim3(M_/128, C_/128), 256, 0, stream>>>(qb, Wo, bo, pair_repr, out, M_, C_, C_);
  // 7. y = LN2(pr) -> qb
  ln_k<<<dim3(M_/4), 256, 0, stream>>>(out, g2, be2, qb);
  // 8. h = relu(y@W1.T + b1) -> hb
  gemm_nt<true,false><<<dim3(M_/128, F_/128), 256, 0, stream>>>(qb, W1, b1, nullptr, hb, M_, F_, C_);
  // 9. out = pr + h@W2.T + b2 -> d_out (R aliases O: same-thread read-then-write only)
  gemm_nt<false,true><<<dim3(M_/128, C_/128), 256, 0, stream>>>(hb, W2, b2, out, out, M_, C_, F_);
}

// Round 2
// 564.598 us; speedup vs baseline: 2.4382x; 2.4382x over previous
//
#include <hip/hip_runtime.h>

#define L_ 256
#define C_ 256
#define H_ 8
#define D_ 32
#define F_ 512
#define M_ (L_*L_)   // 65536 rows
#define SCALE_ 0.17677669529663687f

typedef __attribute__((ext_vector_type(8))) short v8s;   // 8 bf16 = 16B
typedef __attribute__((ext_vector_type(4))) float v4f;   // MFMA acc

__device__ __forceinline__ ushort f2bf(float f) {
  union { float f; unsigned u; } v; v.f = f;
  unsigned r = v.u + 0x7FFFu + ((v.u >> 16) & 1u);   // RNE
  return (ushort)(r >> 16);
}

// ---------------- LayerNorm over last dim (C=256), one wave per row ----------
__global__ __launch_bounds__(256) void ln_k(const float* __restrict__ in,
    const float* __restrict__ g, const float* __restrict__ b,
    ushort* __restrict__ out) {
  int wid = threadIdx.x >> 6, lane = threadIdx.x & 63;
  size_t row = (size_t)blockIdx.x * 4 + wid;
  const float* x = in + row * C_;
  float4 v = *(const float4*)&x[lane*4];
  float s  = v.x + v.y + v.z + v.w;
  float s2 = v.x*v.x + v.y*v.y + v.z*v.z + v.w*v.w;
  #pragma unroll
  for (int off = 1; off < 64; off <<= 1) {
    s  += __shfl_xor(s,  off);
    s2 += __shfl_xor(s2, off);
  }
  float mean = s * (1.0f/C_);
  float var  = s2 * (1.0f/C_) - mean*mean;
  float inv  = rsqrtf(var + 1e-5f);
  float4 gg = *(const float4*)&g[lane*4];
  float4 bb = *(const float4*)&b[lane*4];
  ushort4 o;
  o.x = f2bf((v.x-mean)*inv*gg.x + bb.x);
  o.y = f2bf((v.y-mean)*inv*gg.y + bb.y);
  o.z = f2bf((v.z-mean)*inv*gg.z + bb.z);
  o.w = f2bf((v.w-mean)*inv*gg.w + bb.w);
  *(ushort4*)&out[row*C_ + lane*4] = o;
}

// ---------------- bf16 MFMA NT GEMM: O[m,n] = sum_k A[m,k]*W[n,k] + bias[n] --
// A bf16 [M,K]; W fp32 [N,K] cast to bf16 during staging. 128x128 tile, BK=32.
template<bool OUTBF16, bool RELU, bool ADD>
__global__ __launch_bounds__(256) void gemm_bf16(
    const ushort* __restrict__ A, const float* __restrict__ W,
    const float* __restrict__ bias, const float* __restrict__ R,
    void* __restrict__ Optr, int M, int N, int K) {
  __shared__ __align__(16) ushort As[128][40];  // pad: row stride 80B -> ~2-way
  __shared__ __align__(16) ushort Bs[128][40];
  const int bm = blockIdx.x * 128;
  const int bn = blockIdx.y * 128;
  const int t  = threadIdx.x;
  const int lane = t & 63, w = t >> 6;
  const int wm = (w >> 1) * 64, wn = (w & 1) * 64;
  const int lg = lane >> 4, lc = lane & 15;
  const int srow = t >> 1, shalf = (t & 1) * 16;

  v4f acc[4][4];
  #pragma unroll
  for (int i = 0; i < 4; ++i)
    #pragma unroll
    for (int j = 0; j < 4; ++j) acc[i][j] = (v4f){0.f,0.f,0.f,0.f};

  for (int k0 = 0; k0 < K; k0 += 32) {
    // stage A: 16 bf16 per thread
    v8s a0 = *(const v8s*)&A[(size_t)(bm+srow)*K + k0 + shalf];
    v8s a1 = *(const v8s*)&A[(size_t)(bm+srow)*K + k0 + shalf + 8];
    // stage W: 16 fp32 -> bf16 per thread
    const float* wp = &W[(size_t)(bn+srow)*K + k0 + shalf];
    float wf[16];
    *(float4*)&wf[0]  = *(const float4*)(wp);
    *(float4*)&wf[4]  = *(const float4*)(wp+4);
    *(float4*)&wf[8]  = *(const float4*)(wp+8);
    *(float4*)&wf[12] = *(const float4*)(wp+12);
    ushort wb[16];
    #pragma unroll
    for (int u = 0; u < 16; ++u) wb[u] = f2bf(wf[u]);
    *(v8s*)&As[srow][shalf]   = a0;
    *(v8s*)&As[srow][shalf+8] = a1;
    *(v8s*)&Bs[srow][shalf]   = *(v8s*)&wb[0];
    *(v8s*)&Bs[srow][shalf+8] = *(v8s*)&wb[8];
    __syncthreads();
    v8s af[4], bf_[4];
    #pragma unroll
    for (int mi = 0; mi < 4; ++mi)
      af[mi] = *(const v8s*)&As[wm + mi*16 + lc][lg*8];
    #pragma unroll
    for (int ni = 0; ni < 4; ++ni)
      bf_[ni] = *(const v8s*)&Bs[wn + ni*16 + lc][lg*8];
    #pragma unroll
    for (int mi = 0; mi < 4; ++mi)
      #pragma unroll
      for (int ni = 0; ni < 4; ++ni)
        acc[mi][ni] = __builtin_amdgcn_mfma_f32_16x16x32_bf16(af[mi], bf_[ni], acc[mi][ni], 0, 0, 0);
    __syncthreads();
  }
  // epilogue: C/D layout col=lane&15, row=(lane>>4)*4+r
  #pragma unroll
  for (int mi = 0; mi < 4; ++mi) {
    int mrow = bm + wm + mi*16 + lg*4;
    #pragma unroll
    for (int ni = 0; ni < 4; ++ni) {
      int ncol = bn + wn + ni*16 + lc;
      float bv = bias[ncol];
      #pragma unroll
      for (int r = 0; r < 4; ++r) {
        float o = acc[mi][ni][r] + bv;
        if (RELU) o = fmaxf(o, 0.f);
        size_t idx = (size_t)(mrow + r) * N + ncol;
        if (ADD) o += R[idx];
        if (OUTBF16) ((ushort*)Optr)[idx] = f2bf(o);
        else         ((float*)Optr)[idx]  = o;
      }
    }
  }
}

// ---------------- fused MFMA flash attention per (j,h) -----------------------
// q,k,v bf16 [M, C] with row m=i*L+j, col h*D+d. 4 waves x 64 q-rows.
__global__ __launch_bounds__(256) void attn_mfma(
    const ushort* __restrict__ q, const ushort* __restrict__ k,
    const ushort* __restrict__ v, const float* __restrict__ bias,
    const int* __restrict__ mask, ushort* __restrict__ attn) {
  __shared__ __align__(16) ushort Ks[64][40];     // [key][d]
  __shared__ __align__(16) ushort Vt[32][72];     // [d][key]
  __shared__ __align__(16) ushort P[4][64][72];   // per-wave [qrow][key]
  const int j = blockIdx.x >> 3, h = blockIdx.x & 7;
  const int t = threadIdx.x, w = t >> 6, lane = t & 63;
  const int lg = lane >> 4, lc = lane & 15;
  const int srow = t >> 2, sq = (t & 3) * 8;      // staging coords

  // Q fragments in registers (read before any aliased write)
  v8s qf[4];
  #pragma unroll
  for (int mi = 0; mi < 4; ++mi) {
    int i = w*64 + mi*16 + lc;
    qf[mi] = *(const v8s*)&q[((size_t)i*L_ + j)*C_ + h*D_ + lg*8];
  }
  v4f acc[4][2];
  float m_r[4][4], l_r[4][4];
  #pragma unroll
  for (int mi = 0; mi < 4; ++mi) {
    acc[mi][0] = (v4f){0.f,0.f,0.f,0.f};
    acc[mi][1] = (v4f){0.f,0.f,0.f,0.f};
    #pragma unroll
    for (int r = 0; r < 4; ++r) { m_r[mi][r] = -1e30f; l_r[mi][r] = 0.f; }
  }

  for (int kt = 0; kt < 4; ++kt) {
    // stage K tile + transposed V tile
    {
      int kg = kt*64 + srow;
      size_t goff = ((size_t)kg*L_ + j)*C_ + h*D_ + sq;
      *(v8s*)&Ks[srow][sq] = *(const v8s*)&k[goff];
      v8s vv = *(const v8s*)&v[goff];
      #pragma unroll
      for (int u = 0; u < 8; ++u) Vt[sq+u][srow] = (ushort)vv[u];
    }
    __syncthreads();

    // S = Q K^T  (16 MFMAs per wave)
    v4f s[4][4];
    v8s kf[4];
    #pragma unroll
    for (int ni = 0; ni < 4; ++ni)
      kf[ni] = *(const v8s*)&Ks[ni*16 + lc][lg*8];
    #pragma unroll
    for (int mi = 0; mi < 4; ++mi)
      #pragma unroll
      for (int ni = 0; ni < 4; ++ni)
        s[mi][ni] = __builtin_amdgcn_mfma_f32_16x16x32_bf16(qf[mi], kf[ni], (v4f){0.f,0.f,0.f,0.f}, 0, 0, 0);

    // scale + bias + mask + online softmax (row spread over 16 lanes x 4 ni)
    #pragma unroll
    for (int mi = 0; mi < 4; ++mi) {
      #pragma unroll
      for (int r = 0; r < 4; ++r) {
        int i = w*64 + mi*16 + lg*4 + r;
        const float* brow = bias + ((size_t)h*L_ + i)*L_;
        const int*   mrow = mask + (size_t)i*L_;
        float mloc = -1e30f;
        #pragma unroll
        for (int ni = 0; ni < 4; ++ni) {
          int kc = kt*64 + ni*16 + lc;
          float sv = s[mi][ni][r] * SCALE_ + brow[kc];
          if (mrow[kc] == 0) sv = -1e30f;
          s[mi][ni][r] = sv;
          mloc = fmaxf(mloc, sv);
        }
        #pragma unroll
        for (int off = 1; off < 16; off <<= 1) mloc = fmaxf(mloc, __shfl_xor(mloc, off));
        float newm = fmaxf(m_r[mi][r], mloc);
        float corr = __expf(m_r[mi][r] - newm);
        float ps = 0.f;
        #pragma unroll
        for (int ni = 0; ni < 4; ++ni) {
          float p = __expf(s[mi][ni][r] - newm);
          s[mi][ni][r] = p;
          ps += p;
        }
        #pragma unroll
        for (int off = 1; off < 16; off <<= 1) ps += __shfl_xor(ps, off);
        l_r[mi][r] = l_r[mi][r]*corr + ps;
        m_r[mi][r] = newm;
        acc[mi][0][r] *= corr;
        acc[mi][1][r] *= corr;
        // write P row slice as bf16
        #pragma unroll
        for (int ni = 0; ni < 4; ++ni)
          P[w][mi*16 + lg*4 + r][ni*16 + lc] = f2bf(s[mi][ni][r]);
      }
    }
    __syncthreads();   // P visible wave-wide (and Ks/Vt reads done)

    // O += P V  (16 MFMAs per wave)
    #pragma unroll
    for (int mi = 0; mi < 4; ++mi)
      #pragma unroll
      for (int ks = 0; ks < 2; ++ks) {
        v8s pa = *(const v8s*)&P[w][mi*16 + lc][ks*32 + lg*8];
        #pragma unroll
        for (int nd = 0; nd < 2; ++nd) {
          v8s vbf = *(const v8s*)&Vt[nd*16 + lc][ks*32 + lg*8];
          acc[mi][nd] = __builtin_amdgcn_mfma_f32_16x16x32_bf16(pa, vbf, acc[mi][nd], 0, 0, 0);
        }
      }
    __syncthreads();   // before next tile restage
  }

  // normalize + write (aliases q buffer: own slice only, Q already in regs)
  #pragma unroll
  for (int mi = 0; mi < 4; ++mi)
    #pragma unroll
    for (int r = 0; r < 4; ++r) {
      int i = w*64 + mi*16 + lg*4 + r;
      float inv = 1.0f / l_r[mi][r];
      #pragma unroll
      for (int nd = 0; nd < 2; ++nd)
        attn[((size_t)i*L_ + j)*C_ + h*D_ + nd*16 + lc] = f2bf(acc[mi][nd][r] * inv);
    }
}

extern "C" void kernel_launch(void* const* d_in, const int* in_sizes, int n_in,
                              void* d_out, int out_size, void* d_ws, size_t ws_size,
                              hipStream_t stream) {
  const float* pair_repr = (const float*)d_in[0];
  const float* pair_bias = (const float*)d_in[1];
  const float* Wq = (const float*)d_in[2];
  const float* bq = (const float*)d_in[3];
  const float* Wk = (const float*)d_in[4];
  const float* bk = (const float*)d_in[5];
  const float* Wv = (const float*)d_in[6];
  const float* bv = (const float*)d_in[7];
  const float* Wo = (const float*)d_in[8];
  const float* bo = (const float*)d_in[9];
  const float* W1 = (const float*)d_in[10];
  const float* b1 = (const float*)d_in[11];
  const float* W2 = (const float*)d_in[12];
  const float* b2 = (const float*)d_in[13];
  const float* g1 = (const float*)d_in[14];
  const float* be1= (const float*)d_in[15];
  const float* g2 = (const float*)d_in[16];
  const float* be2= (const float*)d_in[17];
  const int* mask = (const int*)d_in[18];
  float* out = (float*)d_out;

  // ws layout (bf16 buffers), 192MB total
  ushort* xb = (ushort*)d_ws;                       // [M,C] x, later y
  ushort* qb = xb + (size_t)M_*C_;                  // q -> attn-out
  ushort* kb = qb + (size_t)M_*C_;
  ushort* vb = kb + (size_t)M_*C_;
  ushort* hb = vb + (size_t)M_*C_;                  // [M,F] ff hidden

  // 1. x = LN1(pair_repr)
  ln_k<<<dim3(M_/4), 256, 0, stream>>>(pair_repr, g1, be1, xb);
  // 2-4. q,k,v projections (bf16 out)
  gemm_bf16<true,false,false><<<dim3(M_/128, C_/128), 256, 0, stream>>>(xb, Wq, bq, nullptr, qb, M_, C_, C_);
  gemm_bf16<true,false,false><<<dim3(M_/128, C_/128), 256, 0, stream>>>(xb, Wk, bk, nullptr, kb, M_, C_, C_);
  gemm_bf16<true,false,false><<<dim3(M_/128, C_/128), 256, 0, stream>>>(xb, Wv, bv, nullptr, vb, M_, C_, C_);
  // 5. attention -> qb (in place over q)
  attn_mfma<<<dim3(L_*H_), 256, 0, stream>>>(qb, kb, vb, pair_bias, mask, qb);
  // 6. pr = attn@Wo.T + bo + pair_repr -> d_out (fp32)
  gemm_bf16<false,false,true><<<dim3(M_/128, C_/128), 256, 0, stream>>>(qb, Wo, bo, pair_repr, out, M_, C_, C_);
  // 7. y = LN2(pr) -> xb
  ln_k<<<dim3(M_/4), 256, 0, stream>>>(out, g2, be2, xb);
  // 8. h = relu(y@W1.T + b1) -> hb (bf16)
  gemm_bf16<true,true,false><<<dim3(M_/128, F_/128), 256, 0, stream>>>(xb, W1, b1, nullptr, hb, M_, F_, C_);
  // 9. out = pr + h@W2.T + b2 -> d_out (fp32, R aliases O per-thread)
  gemm_bf16<false,false,true><<<dim3(M_/128, C_/128), 256, 0, stream>>>(hb, W2, b2, out, out, M_, C_, F_);
}

// Round 3
// 382.620 us; speedup vs baseline: 3.5979x; 1.4756x over previous
//
#include <hip/hip_runtime.h>

#define L_ 256
#define C_ 256
#define H_ 8
#define D_ 32
#define F_ 512
#define M_ (L_*L_)   // 65536 rows
#define SCALE_ 0.17677669529663687f

typedef __attribute__((ext_vector_type(8))) short v8s;   // 8 bf16 = 16B
typedef __attribute__((ext_vector_type(4))) float v4f;   // MFMA acc

__device__ __forceinline__ ushort f2bf(float f) {
  union { float f; unsigned u; } v; v.f = f;
  unsigned r = v.u + 0x7FFFu + ((v.u >> 16) & 1u);   // RNE
  return (ushort)(r >> 16);
}

// ---------------- prep: weight cast/concat + masked bias ---------------------
__global__ __launch_bounds__(256) void prep_k(
    const float* __restrict__ Wq, const float* __restrict__ Wk,
    const float* __restrict__ Wv, const float* __restrict__ Wo,
    const float* __restrict__ bq, const float* __restrict__ bk,
    const float* __restrict__ bv,
    const float* __restrict__ bias, const int* __restrict__ mask,
    ushort* __restrict__ Wqkvb, ushort* __restrict__ Wob,
    float* __restrict__ bqkv, float* __restrict__ bM) {
  int idx = blockIdx.x * 256 + threadIdx.x;     // vec4 index
  if (idx < 49152) {                             // Wqkv: 768x256
    int e = idx * 4; int n = e >> 8; int k = e & 255;
    const float* src = n < 256 ? &Wq[n*256 + k]
                     : n < 512 ? &Wk[(n-256)*256 + k]
                               : &Wv[(n-512)*256 + k];
    float4 f = *(const float4*)src;
    ushort4 o = { f2bf(f.x), f2bf(f.y), f2bf(f.z), f2bf(f.w) };
    *(ushort4*)&Wqkvb[e] = o;
  } else if (idx < 65536) {                      // Wo: 256x256
    int e = (idx - 49152) * 4;
    float4 f = *(const float4*)&Wo[e];
    ushort4 o = { f2bf(f.x), f2bf(f.y), f2bf(f.z), f2bf(f.w) };
    *(ushort4*)&Wob[e] = o;
  } else if (idx < 196608) {                     // bM: H*L*L floats
    int e = (idx - 65536) * 4;
    float4 b4 = *(const float4*)&bias[e];
    int4  m4 = *(const int4*)&mask[e & 65535];
    float4 o;
    o.x = m4.x ? b4.x : -1e30f;
    o.y = m4.y ? b4.y : -1e30f;
    o.z = m4.z ? b4.z : -1e30f;
    o.w = m4.w ? b4.w : -1e30f;
    *(float4*)&bM[e] = o;
  } else if (idx < 196800) {                     // bqkv: 768
    int e = (idx - 196608) * 4;
    const float* src = e < 256 ? &bq[e] : e < 512 ? &bk[e-256] : &bv[e-512];
    *(float4*)&bqkv[e] = *(const float4*)src;
  }
}

// ---------------- LayerNorm over last dim (C=256), one wave per row ----------
__global__ __launch_bounds__(256) void ln_k(const float* __restrict__ in,
    const float* __restrict__ g, const float* __restrict__ b,
    ushort* __restrict__ out) {
  int wid = threadIdx.x >> 6, lane = threadIdx.x & 63;
  size_t row = (size_t)blockIdx.x * 4 + wid;
  const float* x = in + row * C_;
  float4 v = *(const float4*)&x[lane*4];
  float s  = v.x + v.y + v.z + v.w;
  float s2 = v.x*v.x + v.y*v.y + v.z*v.z + v.w*v.w;
  #pragma unroll
  for (int off = 1; off < 64; off <<= 1) {
    s  += __shfl_xor(s,  off);
    s2 += __shfl_xor(s2, off);
  }
  float mean = s * (1.0f/C_);
  float var  = s2 * (1.0f/C_) - mean*mean;
  float inv  = rsqrtf(var + 1e-5f);
  float4 gg = *(const float4*)&g[lane*4];
  float4 bb = *(const float4*)&b[lane*4];
  ushort4 o;
  o.x = f2bf((v.x-mean)*inv*gg.x + bb.x);
  o.y = f2bf((v.y-mean)*inv*gg.y + bb.y);
  o.z = f2bf((v.z-mean)*inv*gg.z + bb.z);
  o.w = f2bf((v.w-mean)*inv*gg.w + bb.w);
  *(ushort4*)&out[row*C_ + lane*4] = o;
}

// ---------------- bf16 MFMA NT GEMM: O[m,n] = sum_k A[m,k]*W[n,k] + bias[n] --
template<bool WBF16, bool OUTBF16, bool RELU, bool ADD>
__global__ __launch_bounds__(256) void gemm2(
    const ushort* __restrict__ A, const void* __restrict__ Wp,
    const float* __restrict__ bias, const float* __restrict__ R,
    void* __restrict__ Optr, int M, int N, int K, int lda, int ldo) {
  __shared__ __align__(16) ushort As[128][40];
  __shared__ __align__(16) ushort Bs[128][40];
  const int bm = blockIdx.x * 128;
  const int bn = blockIdx.y * 128;
  const int t  = threadIdx.x;
  const int lane = t & 63, w = t >> 6;
  const int wm = (w >> 1) * 64, wn = (w & 1) * 64;
  const int lg = lane >> 4, lc = lane & 15;
  const int srow = t >> 1, shalf = (t & 1) * 16;

  v4f acc[4][4];
  #pragma unroll
  for (int i = 0; i < 4; ++i)
    #pragma unroll
    for (int j = 0; j < 4; ++j) acc[i][j] = (v4f){0.f,0.f,0.f,0.f};

  for (int k0 = 0; k0 < K; k0 += 32) {
    v8s a0 = *(const v8s*)&A[(size_t)(bm+srow)*lda + k0 + shalf];
    v8s a1 = *(const v8s*)&A[(size_t)(bm+srow)*lda + k0 + shalf + 8];
    if (WBF16) {
      const ushort* Wb = (const ushort*)Wp;
      v8s w0 = *(const v8s*)&Wb[(size_t)(bn+srow)*K + k0 + shalf];
      v8s w1 = *(const v8s*)&Wb[(size_t)(bn+srow)*K + k0 + shalf + 8];
      *(v8s*)&As[srow][shalf]   = a0;
      *(v8s*)&As[srow][shalf+8] = a1;
      *(v8s*)&Bs[srow][shalf]   = w0;
      *(v8s*)&Bs[srow][shalf+8] = w1;
    } else {
      const float* wp = &((const float*)Wp)[(size_t)(bn+srow)*K + k0 + shalf];
      float wf[16];
      *(float4*)&wf[0]  = *(const float4*)(wp);
      *(float4*)&wf[4]  = *(const float4*)(wp+4);
      *(float4*)&wf[8]  = *(const float4*)(wp+8);
      *(float4*)&wf[12] = *(const float4*)(wp+12);
      ushort wb[16];
      #pragma unroll
      for (int u = 0; u < 16; ++u) wb[u] = f2bf(wf[u]);
      *(v8s*)&As[srow][shalf]   = a0;
      *(v8s*)&As[srow][shalf+8] = a1;
      *(v8s*)&Bs[srow][shalf]   = *(v8s*)&wb[0];
      *(v8s*)&Bs[srow][shalf+8] = *(v8s*)&wb[8];
    }
    __syncthreads();
    v8s af[4], bf_[4];
    #pragma unroll
    for (int mi = 0; mi < 4; ++mi)
      af[mi] = *(const v8s*)&As[wm + mi*16 + lc][lg*8];
    #pragma unroll
    for (int ni = 0; ni < 4; ++ni)
      bf_[ni] = *(const v8s*)&Bs[wn + ni*16 + lc][lg*8];
    #pragma unroll
    for (int mi = 0; mi < 4; ++mi)
      #pragma unroll
      for (int ni = 0; ni < 4; ++ni)
        acc[mi][ni] = __builtin_amdgcn_mfma_f32_16x16x32_bf16(af[mi], bf_[ni], acc[mi][ni], 0, 0, 0);
    __syncthreads();
  }
  #pragma unroll
  for (int mi = 0; mi < 4; ++mi) {
    int mrow = bm + wm + mi*16 + lg*4;
    #pragma unroll
    for (int ni = 0; ni < 4; ++ni) {
      int ncol = bn + wn + ni*16 + lc;
      float bv = bias[ncol];
      #pragma unroll
      for (int r = 0; r < 4; ++r) {
        float o = acc[mi][ni][r] + bv;
        if (RELU) o = fmaxf(o, 0.f);
        size_t idx = (size_t)(mrow + r) * ldo + ncol;
        if (ADD) o += R[idx];
        if (OUTBF16) ((ushort*)Optr)[idx] = f2bf(o);
        else         ((float*)Optr)[idx]  = o;
      }
    }
  }
}

// ---------------- fused attention per (j,h), swapped-QK^T, 1 barrier --------
// qkv bf16 [M,768]: q at col 0, k at 256, v at 512; row m = i*L + j.
__global__ __launch_bounds__(256) void attn2(
    const ushort* __restrict__ qkv, const float* __restrict__ bM,
    ushort* __restrict__ oq) {
  __shared__ __align__(16) ushort Vt[32][264];    // [d][key], all 256 keys
  __shared__ __align__(16) ushort P[4][16][136];  // per-wave [qrow16][key]
  const int j = blockIdx.x >> 3, h = blockIdx.x & 7;
  const int t = threadIdx.x, w = t >> 6, lane = t & 63;
  const int lg = lane >> 4, lc = lane & 15;

  // stage V transposed (once, all keys)
  {
    int skey = t >> 2, sd = (t & 3) * 8;
    #pragma unroll
    for (int p = 0; p < 4; ++p) {
      int kk = p*64 + skey;
      v8s vv = *(const v8s*)&qkv[((size_t)kk*L_ + j)*768 + 512 + h*D_ + sd];
      #pragma unroll
      for (int u = 0; u < 8; ++u) Vt[sd+u][kk] = (ushort)vv[u];
    }
  }
  __syncthreads();

  #pragma unroll 1
  for (int mi = 0; mi < 4; ++mi) {
    const int qrow = w*64 + mi*16 + lc;
    // Q fragment (L1-resident after first wave touches it)
    v8s qf = *(const v8s*)&qkv[((size_t)qrow*L_ + j)*768 + h*D_ + lg*8];
    // S^T = K Q^T : lane owns column qrow, rows = keys (lg*4+r per 16-tile)
    v4f s[16];
    #pragma unroll
    for (int kn = 0; kn < 16; ++kn) {
      v8s kf = *(const v8s*)&qkv[((size_t)(kn*16+lc)*L_ + j)*768 + 256 + h*D_ + lg*8];
      s[kn] = __builtin_amdgcn_mfma_f32_16x16x32_bf16(kf, qf, (v4f){0.f,0.f,0.f,0.f}, 0, 0, 0);
    }
    // scale + masked-bias + max (in-reg 64 + 2 shuffles)
    const float* brow = bM + ((size_t)h*L_ + qrow)*L_;
    float mx = -1e30f;
    #pragma unroll
    for (int kn = 0; kn < 16; ++kn) {
      float4 b4 = *(const float4*)&brow[kn*16 + lg*4];
      s[kn][0] = fmaf(s[kn][0], SCALE_, b4.x);
      s[kn][1] = fmaf(s[kn][1], SCALE_, b4.y);
      s[kn][2] = fmaf(s[kn][2], SCALE_, b4.z);
      s[kn][3] = fmaf(s[kn][3], SCALE_, b4.w);
      mx = fmaxf(mx, fmaxf(fmaxf(s[kn][0], s[kn][1]), fmaxf(s[kn][2], s[kn][3])));
    }
    mx = fmaxf(mx, __shfl_xor(mx, 16));
    mx = fmaxf(mx, __shfl_xor(mx, 32));
    // exp + sum
    float l = 0.f;
    #pragma unroll
    for (int kn = 0; kn < 16; ++kn) {
      s[kn][0] = __expf(s[kn][0] - mx);
      s[kn][1] = __expf(s[kn][1] - mx);
      s[kn][2] = __expf(s[kn][2] - mx);
      s[kn][3] = __expf(s[kn][3] - mx);
      l += (s[kn][0] + s[kn][1]) + (s[kn][2] + s[kn][3]);
    }
    l += __shfl_xor(l, 16);
    l += __shfl_xor(l, 32);
    // P store (wave-private): P[qrow16=lc][key]
    #pragma unroll
    for (int kn = 0; kn < 16; ++kn) {
      uint lo = (uint)f2bf(s[kn][0]) | ((uint)f2bf(s[kn][1]) << 16);
      uint hi = (uint)f2bf(s[kn][2]) | ((uint)f2bf(s[kn][3]) << 16);
      uint* dst = (uint*)&P[w][lc][kn*16 + lg*4];
      dst[0] = lo; dst[1] = hi;
    }
    // O^T = V^T P^T : 16 MFMAs
    v4f a0 = (v4f){0.f,0.f,0.f,0.f}, a1 = (v4f){0.f,0.f,0.f,0.f};
    #pragma unroll
    for (int kc = 0; kc < 8; ++kc) {
      v8s pf = *(const v8s*)&P[w][lc][kc*32 + lg*8];
      v8s v0 = *(const v8s*)&Vt[lc][kc*32 + lg*8];
      v8s v1 = *(const v8s*)&Vt[16 + lc][kc*32 + lg*8];
      a0 = __builtin_amdgcn_mfma_f32_16x16x32_bf16(v0, pf, a0, 0, 0, 0);
      a1 = __builtin_amdgcn_mfma_f32_16x16x32_bf16(v1, pf, a1, 0, 0, 0);
    }
    // normalize + write own column (d = tile*16 + lg*4 + r)
    float inv = 1.0f / l;
    size_t ob = ((size_t)qrow*L_ + j)*768 + h*D_;
    #pragma unroll
    for (int i = 0; i < 2; ++i) {
      uint w0 = (uint)f2bf(a0[2*i]*inv) | ((uint)f2bf(a0[2*i+1]*inv) << 16);
      uint w1 = (uint)f2bf(a1[2*i]*inv) | ((uint)f2bf(a1[2*i+1]*inv) << 16);
      *(uint*)&oq[ob + lg*4 + 2*i]      = w0;
      *(uint*)&oq[ob + 16 + lg*4 + 2*i] = w1;
    }
  }
}

extern "C" void kernel_launch(void* const* d_in, const int* in_sizes, int n_in,
                              void* d_out, int out_size, void* d_ws, size_t ws_size,
                              hipStream_t stream) {
  const float* pair_repr = (const float*)d_in[0];
  const float* pair_bias = (const float*)d_in[1];
  const float* Wq = (const float*)d_in[2];
  const float* bq = (const float*)d_in[3];
  const float* Wk = (const float*)d_in[4];
  const float* bk = (const float*)d_in[5];
  const float* Wv = (const float*)d_in[6];
  const float* bv = (const float*)d_in[7];
  const float* Wo = (const float*)d_in[8];
  const float* bo = (const float*)d_in[9];
  const float* W1 = (const float*)d_in[10];
  const float* b1 = (const float*)d_in[11];
  const float* W2 = (const float*)d_in[12];
  const float* b2 = (const float*)d_in[13];
  const float* g1 = (const float*)d_in[14];
  const float* be1= (const float*)d_in[15];
  const float* g2 = (const float*)d_in[16];
  const float* be2= (const float*)d_in[17];
  const int* mask = (const int*)d_in[18];
  float* out = (float*)d_out;

  char* wsb = (char*)d_ws;
  ushort* xb   = (ushort*)wsb;                      // [M,256] bf16: x, later y
  ushort* qkvb = (ushort*)(wsb + 33554432);         // [M,768] bf16
  char*   hbB  = wsb + 134217728;                   // [M,512] bf16 region
  ushort* hb   = (ushort*)hbB;
  ushort* Wqkvb = hb;                               // 196608 us (dead at step 8)
  ushort* Wob   = hb + 196608;                      // 65536 us
  float*  bqkv  = (float*)(hbB + 524288);           // 768 f
  float*  bMp   = bqkv + 768;                       // 524288 f

  // 0. prep: weights -> bf16, bias+mask fuse
  prep_k<<<dim3(769), 256, 0, stream>>>(Wq, Wk, Wv, Wo, bq, bk, bv,
                                        pair_bias, mask, Wqkvb, Wob, bqkv, bMp);
  // 1. x = LN1(pair_repr)
  ln_k<<<dim3(M_/4), 256, 0, stream>>>(pair_repr, g1, be1, xb);
  // 2. fused qkv projection -> qkvb
  gemm2<true,true,false,false><<<dim3(M_/128, 6), 256, 0, stream>>>(
      xb, Wqkvb, bqkv, nullptr, qkvb, M_, 768, C_, C_, 768);
  // 3. attention (in place into q-third)
  attn2<<<dim3(L_*H_), 256, 0, stream>>>(qkvb, bMp, qkvb);
  // 4. pr = attn@Wo.T + bo + pair_repr -> d_out (fp32)
  gemm2<true,false,false,true><<<dim3(M_/128, 2), 256, 0, stream>>>(
      qkvb, Wob, bo, pair_repr, out, M_, C_, C_, 768, C_);
  // 5. y = LN2(pr) -> xb
  ln_k<<<dim3(M_/4), 256, 0, stream>>>(out, g2, be2, xb);
  // 6. h = relu(y@W1.T + b1) -> hb (overwrites weight scratch; W1 read from global)
  gemm2<false,true,true,false><<<dim3(M_/128, 4), 256, 0, stream>>>(
      xb, W1, b1, nullptr, hb, M_, F_, C_, C_, F_);
  // 7. out = pr + h@W2.T + b2 -> d_out
  gemm2<false,false,false,true><<<dim3(M_/128, 2), 256, 0, stream>>>(
      hb, W2, b2, out, out, M_, C_, F_, F_, C_);
}

// Round 6
// 342.457 us; speedup vs baseline: 4.0198x; 1.1173x over previous
//
#include <hip/hip_runtime.h>

#define L_ 256
#define C_ 256
#define H_ 8
#define D_ 32
#define F_ 512
#define M_ (L_*L_)   // 65536 rows
#define SCALE2_ 0.2550348564624926f   // (1/sqrt(32)) * log2(e)
#define LOG2E_  1.4426950408889634f

typedef __attribute__((ext_vector_type(8))) short v8s;   // 8 bf16 = 16B
typedef __attribute__((ext_vector_type(4))) float v4f;   // MFMA acc

__device__ __forceinline__ ushort f2bf(float f) {
  union { float f; unsigned u; } v; v.f = f;
  unsigned r = v.u + 0x7FFFu + ((v.u >> 16) & 1u);   // RNE
  return (ushort)(r >> 16);
}

// ---------------- prep: weight cast/concat + transposed masked bias ----------
__global__ __launch_bounds__(256) void prep_k(
    const float* __restrict__ Wq, const float* __restrict__ Wk,
    const float* __restrict__ Wv, const float* __restrict__ Wo,
    const float* __restrict__ bq, const float* __restrict__ bk,
    const float* __restrict__ bv,
    const float* __restrict__ bias, const int* __restrict__ mask,
    ushort* __restrict__ Wqkvb, ushort* __restrict__ Wob,
    float* __restrict__ bqkv, float* __restrict__ bMt) {
  int idx = blockIdx.x * 256 + threadIdx.x;
  if (idx < 49152) {                             // Wqkv: 768x256
    int e = idx * 4; int n = e >> 8; int k = e & 255;
    const float* src = n < 256 ? &Wq[n*256 + k]
                     : n < 512 ? &Wk[(n-256)*256 + k]
                               : &Wv[(n-512)*256 + k];
    float4 f = *(const float4*)src;
    ushort4 o = { f2bf(f.x), f2bf(f.y), f2bf(f.z), f2bf(f.w) };
    *(ushort4*)&Wqkvb[e] = o;
  } else if (idx < 65536) {                      // Wo: 256x256
    int e = (idx - 49152) * 4;
    float4 f = *(const float4*)&Wo[e];
    ushort4 o = { f2bf(f.x), f2bf(f.y), f2bf(f.z), f2bf(f.w) };
    *(ushort4*)&Wob[e] = o;
  } else if (idx < 196608) {                     // bMt[h][k][i] = mask? b*log2e : -1e30
    int e = idx - 65536;                         // over [h][k][i4]
    int h = e >> 14, rem = e & 16383;
    int k = rem >> 6, i4 = (rem & 63) * 4;
    float4 o;
    float* po = &o.x;
    #pragma unroll
    for (int u = 0; u < 4; ++u) {
      int i = i4 + u;
      float b = bias[((size_t)h*256 + i)*256 + k];
      int   m = mask[(size_t)i*256 + k];
      po[u] = m ? b * LOG2E_ : -1e30f;
    }
    *(float4*)&bMt[((size_t)h*256 + k)*256 + i4] = o;
  } else if (idx < 196800) {                     // bqkv: 768
    int e = (idx - 196608) * 4;
    const float* src = e < 256 ? &bq[e] : e < 512 ? &bk[e-256] : &bv[e-512];
    *(float4*)&bqkv[e] = *(const float4*)src;
  }
}

// ---------------- LayerNorm over last dim (C=256), one wave per row ----------
__global__ __launch_bounds__(256) void ln_k(const float* __restrict__ in,
    const float* __restrict__ g, const float* __restrict__ b,
    ushort* __restrict__ out) {
  int wid = threadIdx.x >> 6, lane = threadIdx.x & 63;
  size_t row = (size_t)blockIdx.x * 4 + wid;
  const float* x = in + row * C_;
  float4 v = *(const float4*)&x[lane*4];
  float s  = v.x + v.y + v.z + v.w;
  float s2 = v.x*v.x + v.y*v.y + v.z*v.z + v.w*v.w;
  #pragma unroll
  for (int off = 1; off < 64; off <<= 1) {
    s  += __shfl_xor(s,  off);
    s2 += __shfl_xor(s2, off);
  }
  float mean = s * (1.0f/C_);
  float var  = s2 * (1.0f/C_) - mean*mean;
  float inv  = rsqrtf(var + 1e-5f);
  float4 gg = *(const float4*)&g[lane*4];
  float4 bb = *(const float4*)&b[lane*4];
  ushort4 o;
  o.x = f2bf((v.x-mean)*inv*gg.x + bb.x);
  o.y = f2bf((v.y-mean)*inv*gg.y + bb.y);
  o.z = f2bf((v.z-mean)*inv*gg.z + bb.z);
  o.w = f2bf((v.w-mean)*inv*gg.w + bb.w);
  *(ushort4*)&out[row*C_ + lane*4] = o;
}

// ---------------- bf16 MFMA NT GEMM, 1D grid + XCD swizzle, n-fastest -------
// O[m,n] = sum_k A[m,k]*W[n,k] + bias[n]. QKV: scatter-write to [proj][h][j][i][d].
template<bool WBF16, bool OUTBF16, bool RELU, bool ADD, bool QKV>
__global__ __launch_bounds__(256) void gemm2(
    const ushort* __restrict__ A, const void* __restrict__ Wp,
    const float* __restrict__ bias, const float* __restrict__ R,
    void* __restrict__ Optr, int N, int K, int lda, int ldo, int nby) {
  __shared__ __align__(16) ushort As[128][40];
  __shared__ __align__(16) ushort Bs[128][40];
  // XCD-bijective swizzle (grid % 8 == 0), n-fastest decode
  int f = blockIdx.x;
  int sw = (f & 7) * (gridDim.x >> 3) + (f >> 3);
  const int bm = (sw / nby) * 128;
  const int bn = (sw % nby) * 128;
  const int t  = threadIdx.x;
  const int lane = t & 63, w = t >> 6;
  const int wm = (w >> 1) * 64, wn = (w & 1) * 64;
  const int lg = lane >> 4, lc = lane & 15;
  const int srow = t >> 1, shalf = (t & 1) * 16;

  v4f acc[4][4];
  #pragma unroll
  for (int i = 0; i < 4; ++i)
    #pragma unroll
    for (int jj = 0; jj < 4; ++jj) acc[i][jj] = (v4f){0.f,0.f,0.f,0.f};

  for (int k0 = 0; k0 < K; k0 += 32) {
    v8s a0 = *(const v8s*)&A[(size_t)(bm+srow)*lda + k0 + shalf];
    v8s a1 = *(const v8s*)&A[(size_t)(bm+srow)*lda + k0 + shalf + 8];
    if (WBF16) {
      const ushort* Wb = (const ushort*)Wp;
      v8s w0 = *(const v8s*)&Wb[(size_t)(bn+srow)*K + k0 + shalf];
      v8s w1 = *(const v8s*)&Wb[(size_t)(bn+srow)*K + k0 + shalf + 8];
      *(v8s*)&As[srow][shalf]   = a0;
      *(v8s*)&As[srow][shalf+8] = a1;
      *(v8s*)&Bs[srow][shalf]   = w0;
      *(v8s*)&Bs[srow][shalf+8] = w1;
    } else {
      const float* wp = &((const float*)Wp)[(size_t)(bn+srow)*K + k0 + shalf];
      float wf[16];
      *(float4*)&wf[0]  = *(const float4*)(wp);
      *(float4*)&wf[4]  = *(const float4*)(wp+4);
      *(float4*)&wf[8]  = *(const float4*)(wp+8);
      *(float4*)&wf[12] = *(const float4*)(wp+12);
      ushort wb[16];
      #pragma unroll
      for (int u = 0; u < 16; ++u) wb[u] = f2bf(wf[u]);
      *(v8s*)&As[srow][shalf]   = a0;
      *(v8s*)&As[srow][shalf+8] = a1;
      *(v8s*)&Bs[srow][shalf]   = *(v8s*)&wb[0];
      *(v8s*)&Bs[srow][shalf+8] = *(v8s*)&wb[8];
    }
    __syncthreads();
    v8s af[4], bf_[4];
    #pragma unroll
    for (int mi = 0; mi < 4; ++mi)
      af[mi] = *(const v8s*)&As[wm + mi*16 + lc][lg*8];
    #pragma unroll
    for (int ni = 0; ni < 4; ++ni)
      bf_[ni] = *(const v8s*)&Bs[wn + ni*16 + lc][lg*8];
    #pragma unroll
    for (int mi = 0; mi < 4; ++mi)
      #pragma unroll
      for (int ni = 0; ni < 4; ++ni)
        acc[mi][ni] = __builtin_amdgcn_mfma_f32_16x16x32_bf16(af[mi], bf_[ni], acc[mi][ni], 0, 0, 0);
    __syncthreads();
  }
  #pragma unroll
  for (int mi = 0; mi < 4; ++mi) {
    int mrow = bm + wm + mi*16 + lg*4;
    #pragma unroll
    for (int ni = 0; ni < 4; ++ni) {
      int ncol = bn + wn + ni*16 + lc;
      float bv = bias[ncol];
      #pragma unroll
      for (int r = 0; r < 4; ++r) {
        float o = acc[mi][ni][r] + bv;
        if (RELU) o = fmaxf(o, 0.f);
        if (QKV) {
          int m = mrow + r, i = m >> 8, jj = m & 255;
          int c = ncol & 255, proj = ncol >> 8;
          int hh = c >> 5, dd = c & 31;
          size_t idx = (size_t)proj*16777216 + (((size_t)hh*256 + jj)*256 + i)*32 + dd;
          ((ushort*)Optr)[idx] = f2bf(o);
        } else {
          size_t idx = (size_t)(mrow + r) * ldo + ncol;
          if (ADD) o += R[idx];
          if (OUTBF16) ((ushort*)Optr)[idx] = f2bf(o);
          else         ((float*)Optr)[idx]  = o;
        }
      }
    }
  }
}

// ---------------- fused attention per (j,h), head-major layouts --------------
// qt/kt/vt: [h][j][i][d] bf16 (contiguous 16KB per (h,j)). ao: [i*L+j][h*32+d].
__global__ __launch_bounds__(256) void attn3(
    const ushort* __restrict__ qt, const ushort* __restrict__ kt,
    const ushort* __restrict__ vt, const float* __restrict__ bMt,
    ushort* __restrict__ ao) {
  __shared__ __align__(16) ushort Ks[256][40];    // [key][d], pad-40 rows
  __shared__ __align__(16) ushort Vt[32][264];    // [d][key]
  __shared__ __align__(16) ushort P[4*4096];      // per-wave 16 qrows x 256 keys
  const int j = blockIdx.x & 255, h = blockIdx.x >> 8;
  const int t = threadIdx.x, w = t >> 6, lane = t & 63;
  const int lg = lane >> 4, lc = lane & 15;
  const size_t base = ((size_t)(h*256 + j)) * 8192;  // *(256*32)

  // stage K (all 256 keys x 32 d, FULL rows) + V transposed
  {
    const ushort* ksrc = kt + base;
    int krow = t >> 1, kq = (t & 1) * 16;
    *(v8s*)&Ks[krow][kq]           = *(const v8s*)&ksrc[krow*32 + kq];
    *(v8s*)&Ks[krow][kq+8]         = *(const v8s*)&ksrc[krow*32 + kq + 8];
    *(v8s*)&Ks[128 + krow][kq]     = *(const v8s*)&ksrc[(128 + krow)*32 + kq];
    *(v8s*)&Ks[128 + krow][kq+8]   = *(const v8s*)&ksrc[(128 + krow)*32 + kq + 8];
    const ushort* vsrc = vt + base;
    int skey = t >> 2, sd = (t & 3) * 8;
    #pragma unroll
    for (int p = 0; p < 4; ++p) {
      int kk = p*64 + skey;
      v8s vv = *(const v8s*)&vsrc[kk*32 + sd];
      #pragma unroll
      for (int u = 0; u < 8; ++u) Vt[sd+u][kk] = (ushort)vv[u];
    }
  }
  __syncthreads();   // only barrier

  char* Pw = (char*)P + w*8192;
  #pragma unroll 1
  for (int mi = 0; mi < 4; ++mi) {
    const int qrow = w*64 + mi*16 + lc;
    v8s qf = *(const v8s*)&qt[base + qrow*32 + lg*8];
    // S^T = K Q^T (lane owns query column qrow)
    v4f s[16];
    #pragma unroll
    for (int kn = 0; kn < 16; ++kn) {
      v8s kf = *(const v8s*)&Ks[kn*16 + lc][lg*8];
      s[kn] = __builtin_amdgcn_mfma_f32_16x16x32_bf16(kf, qf, (v4f){0.f,0.f,0.f,0.f}, 0, 0, 0);
    }
    // scale(log2e-folded) + masked bias (coalesced) + max
    const float* bb = bMt + ((size_t)h << 16) + qrow;
    float mx = -1e30f;
    #pragma unroll
    for (int kn = 0; kn < 16; ++kn) {
      #pragma unroll
      for (int r = 0; r < 4; ++r) {
        float b = bb[(kn*16 + lg*4 + r) << 8];
        float sv = fmaf(s[kn][r], SCALE2_, b);
        s[kn][r] = sv;
        mx = fmaxf(mx, sv);
      }
    }
    mx = fmaxf(mx, __shfl_xor(mx, 16));
    mx = fmaxf(mx, __shfl_xor(mx, 32));
    // exp2 + sum + P store (row stride 512B, XOR-swizzled bits 4..6)
    float l = 0.f;
    #pragma unroll
    for (int kn = 0; kn < 16; ++kn) {
      float p0 = __builtin_amdgcn_exp2f(s[kn][0] - mx);
      float p1 = __builtin_amdgcn_exp2f(s[kn][1] - mx);
      float p2 = __builtin_amdgcn_exp2f(s[kn][2] - mx);
      float p3 = __builtin_amdgcn_exp2f(s[kn][3] - mx);
      l += (p0 + p1) + (p2 + p3);
      uint2 pk;
      pk.x = (uint)f2bf(p0) | ((uint)f2bf(p1) << 16);
      pk.y = (uint)f2bf(p2) | ((uint)f2bf(p3) << 16);
      uint off = ((uint)lc << 9) + ((uint)kn << 5) + ((uint)lg << 3);
      off ^= (uint)(lc & 7) << 4;
      *(uint2*)(Pw + off) = pk;
    }
    l += __shfl_xor(l, 16);
    l += __shfl_xor(l, 32);
    // O^T = V^T P^T
    v4f a0 = (v4f){0.f,0.f,0.f,0.f}, a1 = (v4f){0.f,0.f,0.f,0.f};
    #pragma unroll
    for (int kc = 0; kc < 8; ++kc) {
      uint off = ((uint)lc << 9) + ((uint)kc << 6) + ((uint)lg << 4);
      off ^= (uint)(lc & 7) << 4;
      v8s pf = *(const v8s*)(Pw + off);
      v8s v0 = *(const v8s*)&Vt[lc][kc*32 + lg*8];
      v8s v1 = *(const v8s*)&Vt[16 + lc][kc*32 + lg*8];
      a0 = __builtin_amdgcn_mfma_f32_16x16x32_bf16(v0, pf, a0, 0, 0, 0);
      a1 = __builtin_amdgcn_mfma_f32_16x16x32_bf16(v1, pf, a1, 0, 0, 0);
    }
    // normalize + write to m-layout attn-out
    float inv = 1.0f / l;
    size_t ob = ((size_t)qrow*256 + j)*256 + h*32;
    #pragma unroll
    for (int i = 0; i < 2; ++i) {
      uint w0 = (uint)f2bf(a0[2*i]*inv) | ((uint)f2bf(a0[2*i+1]*inv) << 16);
      uint w1 = (uint)f2bf(a1[2*i]*inv) | ((uint)f2bf(a1[2*i+1]*inv) << 16);
      *(uint*)&ao[ob + lg*4 + 2*i]      = w0;
      *(uint*)&ao[ob + 16 + lg*4 + 2*i] = w1;
    }
  }
}

extern "C" void kernel_launch(void* const* d_in, const int* in_sizes, int n_in,
                              void* d_out, int out_size, void* d_ws, size_t ws_size,
                              hipStream_t stream) {
  const float* pair_repr = (const float*)d_in[0];
  const float* pair_bias = (const float*)d_in[1];
  const float* Wq = (const float*)d_in[2];
  const float* bq = (const float*)d_in[3];
  const float* Wk = (const float*)d_in[4];
  const float* bk = (const float*)d_in[5];
  const float* Wv = (const float*)d_in[6];
  const float* bv = (const float*)d_in[7];
  const float* Wo = (const float*)d_in[8];
  const float* bo = (const float*)d_in[9];
  const float* W1 = (const float*)d_in[10];
  const float* b1 = (const float*)d_in[11];
  const float* W2 = (const float*)d_in[12];
  const float* b2 = (const float*)d_in[13];
  const float* g1 = (const float*)d_in[14];
  const float* be1= (const float*)d_in[15];
  const float* g2 = (const float*)d_in[16];
  const float* be2= (const float*)d_in[17];
  const int* mask = (const int*)d_in[18];
  float* out = (float*)d_out;

  char* wsb = (char*)d_ws;
  // region A @0 (32MB): xb (LN1 out) -> ao (attn out)
  ushort* xb = (ushort*)wsb;
  ushort* ao = (ushort*)wsb;
  // region B @32MB (32MB): q_t -> y (LN2 out)
  ushort* qt = (ushort*)(wsb + 33554432);
  ushort* yb = qt;
  // region C @64MB (64MB): k_t(@64MB) + v_t(@96MB) -> hb (FF hidden)
  ushort* kt = (ushort*)(wsb + 67108864);
  ushort* vt = (ushort*)(wsb + 100663296);
  ushort* hb = kt;
  // region D @128MB (~3MB): weights + biases + bMt
  char* d0 = wsb + 134217728;
  ushort* Wqkvb = (ushort*)d0;                 // 393216 B
  ushort* Wob   = (ushort*)(d0 + 393216);      // 131072 B
  float*  bqkv  = (float*)(d0 + 524288);       // 3072 B
  float*  bMt   = (float*)(d0 + 1048576);      // 2 MB

  // 0. prep
  prep_k<<<dim3(769), 256, 0, stream>>>(Wq, Wk, Wv, Wo, bq, bk, bv,
                                        pair_bias, mask, Wqkvb, Wob, bqkv, bMt);
  // 1. x = LN1(pair_repr) -> xb
  ln_k<<<dim3(M_/4), 256, 0, stream>>>(pair_repr, g1, be1, xb);
  // 2. qkv projection -> head-major qt/kt/vt (contiguous base = qt)
  gemm2<true,true,false,false,true><<<dim3(3072), 256, 0, stream>>>(
      xb, Wqkvb, bqkv, nullptr, qt, 768, C_, C_, 0, 6);
  // 3. attention -> ao (region A; xb dead)
  attn3<<<dim3(L_*H_), 256, 0, stream>>>(qt, kt, vt, bMt, ao);
  // 4. pr = ao@Wo.T + bo + pair_repr -> d_out (fp32)
  gemm2<true,false,false,true,false><<<dim3(1024), 256, 0, stream>>>(
      ao, Wob, bo, pair_repr, out, C_, C_, C_, C_, 2);
  // 5. y = LN2(pr) -> yb (region B; qt dead)
  ln_k<<<dim3(M_/4), 256, 0, stream>>>(out, g2, be2, yb);
  // 6. h = relu(y@W1.T + b1) -> hb (region C; kt/vt dead)
  gemm2<false,true,true,false,false><<<dim3(2048), 256, 0, stream>>>(
      yb, W1, b1, nullptr, hb, F_, C_, C_, F_, 4);
  // 7. out = pr + h@W2.T + b2 -> d_out
  gemm2<false,false,false,true,false><<<dim3(1024), 256, 0, stream>>>(
      hb, W2, b2, out, out, C_, F_, F_, C_, 2);
}

// Round 7
// 331.813 us; speedup vs baseline: 4.1488x; 1.0321x over previous
//
#include <hip/hip_runtime.h>

#define L_ 256
#define C_ 256
#define H_ 8
#define D_ 32
#define F_ 512
#define M_ (L_*L_)   // 65536 rows
#define SCALE2_ 0.2550348564624926f   // (1/sqrt(32)) * log2(e)
#define LOG2E_  1.4426950408889634f

typedef __attribute__((ext_vector_type(8))) short v8s;   // 8 bf16 = 16B
typedef __attribute__((ext_vector_type(4))) float v4f;   // MFMA acc

__device__ __forceinline__ ushort f2bf(float f) {
  union { float f; unsigned u; } v; v.f = f;
  unsigned r = v.u + 0x7FFFu + ((v.u >> 16) & 1u);   // RNE
  return (ushort)(r >> 16);
}

__device__ __forceinline__ void gload16(const void* g, void* l) {
  __builtin_amdgcn_global_load_lds(
      (const __attribute__((address_space(1))) void*)g,
      (__attribute__((address_space(3))) void*)l, 16, 0, 0);
}

// ---------------- prep: all weights -> bf16, bias retile ---------------------
// sections (vec4 idx): Wqkv 49152 | Wo 16384 | W1 32768 | W2 32768 | bMt2 32768 | bqkv 192
__global__ __launch_bounds__(256) void prep_k(
    const float* __restrict__ Wq, const float* __restrict__ Wk,
    const float* __restrict__ Wv, const float* __restrict__ Wo,
    const float* __restrict__ W1, const float* __restrict__ W2,
    const float* __restrict__ bq, const float* __restrict__ bk,
    const float* __restrict__ bv,
    const float* __restrict__ bias, const int* __restrict__ mask,
    ushort* __restrict__ Wqkvb, ushort* __restrict__ Wob,
    ushort* __restrict__ W1b, ushort* __restrict__ W2b,
    float* __restrict__ bqkv, float* __restrict__ bMt2) {
  int idx = blockIdx.x * 256 + threadIdx.x;
  if (idx < 49152) {                             // Wqkv: 768x256
    int e = idx * 4; int n = e >> 8; int k = e & 255;
    const float* src = n < 256 ? &Wq[n*256 + k]
                     : n < 512 ? &Wk[(n-256)*256 + k]
                               : &Wv[(n-512)*256 + k];
    float4 f = *(const float4*)src;
    ushort4 o = { f2bf(f.x), f2bf(f.y), f2bf(f.z), f2bf(f.w) };
    *(ushort4*)&Wqkvb[e] = o;
  } else if (idx < 65536) {                      // Wo: 256x256
    int e = (idx - 49152) * 4;
    float4 f = *(const float4*)&Wo[e];
    ushort4 o = { f2bf(f.x), f2bf(f.y), f2bf(f.z), f2bf(f.w) };
    *(ushort4*)&Wob[e] = o;
  } else if (idx < 98304) {                      // W1: 512x256
    int e = (idx - 65536) * 4;
    float4 f = *(const float4*)&W1[e];
    ushort4 o = { f2bf(f.x), f2bf(f.y), f2bf(f.z), f2bf(f.w) };
    *(ushort4*)&W1b[e] = o;
  } else if (idx < 131072) {                     // W2: 256x512
    int e = (idx - 98304) * 4;
    float4 f = *(const float4*)&W2[e];
    ushort4 o = { f2bf(f.x), f2bf(f.y), f2bf(f.z), f2bf(f.w) };
    *(ushort4*)&W2b[e] = o;
  } else if (idx < 163840) {                     // bMt2[h][k16][i][r16]
    int e = idx - 131072;                        // (h, kb, i)
    int h = e >> 12, kb = (e >> 8) & 15, i = e & 255;
    const float* bsrc = &bias[((size_t)h*256 + i)*256 + kb*16];
    const int*   msrc = &mask[(size_t)i*256 + kb*16];
    float* dst = &bMt2[(((size_t)h*16 + kb)*256 + i)*16];
    #pragma unroll
    for (int u4 = 0; u4 < 4; ++u4) {
      float4 b4 = *(const float4*)&bsrc[u4*4];
      int4   m4 = *(const int4*)&msrc[u4*4];
      float4 o;
      o.x = m4.x ? b4.x * LOG2E_ : -1e30f;
      o.y = m4.y ? b4.y * LOG2E_ : -1e30f;
      o.z = m4.z ? b4.z * LOG2E_ : -1e30f;
      o.w = m4.w ? b4.w * LOG2E_ : -1e30f;
      *(float4*)&dst[u4*4] = o;
    }
  } else if (idx < 164032) {                     // bqkv: 768
    int e = (idx - 163840) * 4;
    const float* src = e < 256 ? &bq[e] : e < 512 ? &bk[e-256] : &bv[e-512];
    *(float4*)&bqkv[e] = *(const float4*)src;
  }
}

// ---------------- LayerNorm over last dim (C=256), one wave per row ----------
__global__ __launch_bounds__(256) void ln_k(const float* __restrict__ in,
    const float* __restrict__ g, const float* __restrict__ b,
    ushort* __restrict__ out) {
  int wid = threadIdx.x >> 6, lane = threadIdx.x & 63;
  size_t row = (size_t)blockIdx.x * 4 + wid;
  const float* x = in + row * C_;
  float4 v = *(const float4*)&x[lane*4];
  float s  = v.x + v.y + v.z + v.w;
  float s2 = v.x*v.x + v.y*v.y + v.z*v.z + v.w*v.w;
  #pragma unroll
  for (int off = 1; off < 64; off <<= 1) {
    s  += __shfl_xor(s,  off);
    s2 += __shfl_xor(s2, off);
  }
  float mean = s * (1.0f/C_);
  float var  = s2 * (1.0f/C_) - mean*mean;
  float inv  = rsqrtf(var + 1e-5f);
  float4 gg = *(const float4*)&g[lane*4];
  float4 bb = *(const float4*)&b[lane*4];
  ushort4 o;
  o.x = f2bf((v.x-mean)*inv*gg.x + bb.x);
  o.y = f2bf((v.y-mean)*inv*gg.y + bb.y);
  o.z = f2bf((v.z-mean)*inv*gg.z + bb.z);
  o.w = f2bf((v.w-mean)*inv*gg.w + bb.w);
  *(ushort4*)&out[row*C_ + lane*4] = o;
}

// ---------------- bf16 MFMA NT GEMM, global_load_lds staging -----------------
// O[m,n] = sum_k A[m,k]*W[n,k] + bias[n]. QKV: scatter-write to [proj][h][j][i][d].
template<bool OUTBF16, bool RELU, bool ADD, bool QKV>
__global__ __launch_bounds__(256) void gemm3(
    const ushort* __restrict__ A, const ushort* __restrict__ W,
    const float* __restrict__ bias, const float* __restrict__ R,
    void* __restrict__ Optr, int N, int K, int lda, int ldo, int nby) {
  __shared__ __align__(16) ushort As[128][32];   // linear: byte off = t*16 (m97 pattern)
  __shared__ __align__(16) ushort Bs[128][32];
  int f = blockIdx.x;
  int sw = (f & 7) * (gridDim.x >> 3) + (f >> 3);   // XCD-bijective (grid%8==0)
  const int bm = (sw / nby) * 128;
  const int bn = (sw % nby) * 128;
  const int t  = threadIdx.x;
  const int lane = t & 63, w = t >> 6;
  const int wm = (w >> 1) * 64, wn = (w & 1) * 64;
  const int lg = lane >> 4, lc = lane & 15;
  const int sr = t >> 2, sc = (t & 3) * 8;       // round0: row sr; round1: row 64+sr

  char* ldsA0 = (char*)As + w*1024;
  char* ldsA1 = (char*)As + 4096 + w*1024;
  char* ldsB0 = (char*)Bs + w*1024;
  char* ldsB1 = (char*)Bs + 4096 + w*1024;

  v4f acc[4][4];
  #pragma unroll
  for (int i = 0; i < 4; ++i)
    #pragma unroll
    for (int jj = 0; jj < 4; ++jj) acc[i][jj] = (v4f){0.f,0.f,0.f,0.f};

  for (int k0 = 0; k0 < K; k0 += 32) {
    gload16(&A[(size_t)(bm + sr)*lda + k0 + sc],       ldsA0);
    gload16(&A[(size_t)(bm + 64 + sr)*lda + k0 + sc],  ldsA1);
    gload16(&W[(size_t)(bn + sr)*K + k0 + sc],         ldsB0);
    gload16(&W[(size_t)(bn + 64 + sr)*K + k0 + sc],    ldsB1);
    __syncthreads();
    v8s af[4], bf_[4];
    #pragma unroll
    for (int mi = 0; mi < 4; ++mi)
      af[mi] = *(const v8s*)&As[wm + mi*16 + lc][lg*8];
    #pragma unroll
    for (int ni = 0; ni < 4; ++ni)
      bf_[ni] = *(const v8s*)&Bs[wn + ni*16 + lc][lg*8];
    #pragma unroll
    for (int mi = 0; mi < 4; ++mi)
      #pragma unroll
      for (int ni = 0; ni < 4; ++ni)
        acc[mi][ni] = __builtin_amdgcn_mfma_f32_16x16x32_bf16(af[mi], bf_[ni], acc[mi][ni], 0, 0, 0);
    __syncthreads();
  }
  #pragma unroll
  for (int mi = 0; mi < 4; ++mi) {
    int mrow = bm + wm + mi*16 + lg*4;
    #pragma unroll
    for (int ni = 0; ni < 4; ++ni) {
      int ncol = bn + wn + ni*16 + lc;
      float bv = bias[ncol];
      #pragma unroll
      for (int r = 0; r < 4; ++r) {
        float o = acc[mi][ni][r] + bv;
        if (RELU) o = fmaxf(o, 0.f);
        if (QKV) {
          int m = mrow + r, i = m >> 8, jj = m & 255;
          int c = ncol & 255, proj = ncol >> 8;
          int hh = c >> 5, dd = c & 31;
          size_t idx = (size_t)proj*16777216 + (((size_t)hh*256 + jj)*256 + i)*32 + dd;
          ((ushort*)Optr)[idx] = f2bf(o);
        } else {
          size_t idx = (size_t)(mrow + r) * ldo + ncol;
          if (ADD) o += R[idx];
          if (OUTBF16) ((ushort*)Optr)[idx] = f2bf(o);
          else         ((float*)Optr)[idx]  = o;
        }
      }
    }
  }
}

// ---------------- fused attention per (j,h) ---------------------------------
// qt/kt/vt: [h][j][i][d] bf16 (16KB per (h,j)); K direct from global (L1).
// bMt2: [h][k16][i][r16] coalesced float4 bias. ao: [i*L+j][h*32+d].
__global__ __launch_bounds__(256) void attn4(
    const ushort* __restrict__ qt, const ushort* __restrict__ kt,
    const ushort* __restrict__ vt, const float* __restrict__ bMt2,
    ushort* __restrict__ ao) {
  __shared__ __align__(16) ushort Vt[32][264];    // [d][key]
  __shared__ __align__(16) ushort P[4*4096];      // per-wave 16 qrows x 256 keys
  const int j = blockIdx.x & 255, h = blockIdx.x >> 8;
  const int t = threadIdx.x, w = t >> 6, lane = t & 63;
  const int lg = lane >> 4, lc = lane & 15;
  const size_t base = ((size_t)(h*256 + j)) * 8192;  // *(256*32)

  // stage V transposed: thread = 4 keys x 8 d, ushort4 writes
  {
    const ushort* vsrc = vt + base;
    int k4 = (t & 63) * 4, sd = (t >> 6) * 8;
    v8s v0 = *(const v8s*)&vsrc[(k4+0)*32 + sd];
    v8s v1 = *(const v8s*)&vsrc[(k4+1)*32 + sd];
    v8s v2 = *(const v8s*)&vsrc[(k4+2)*32 + sd];
    v8s v3 = *(const v8s*)&vsrc[(k4+3)*32 + sd];
    #pragma unroll
    for (int u = 0; u < 8; ++u) {
      ushort4 q4 = { (ushort)v0[u], (ushort)v1[u], (ushort)v2[u], (ushort)v3[u] };
      *(ushort4*)&Vt[sd+u][k4] = q4;
    }
  }
  __syncthreads();   // only barrier

  const ushort* ksrc = kt + base;
  char* Pw = (char*)P + w*8192;
  #pragma unroll 1
  for (int mi = 0; mi < 4; ++mi) {
    const int qrow = w*64 + mi*16 + lc;
    v8s qf = *(const v8s*)&qt[base + qrow*32 + lg*8];
    // S^T = K Q^T (lane owns query column qrow); K coalesced from global/L1
    v4f s[16];
    #pragma unroll
    for (int kn = 0; kn < 16; ++kn) {
      v8s kf = *(const v8s*)&ksrc[(kn*16 + lc)*32 + lg*8];
      s[kn] = __builtin_amdgcn_mfma_f32_16x16x32_bf16(kf, qf, (v4f){0.f,0.f,0.f,0.f}, 0, 0, 0);
    }
    // scale(log2e-folded) + masked bias (float4 coalesced) + max
    const float* bb = bMt2 + ((size_t)h << 16) + qrow*16;
    float mx = -1e30f;
    #pragma unroll
    for (int kn = 0; kn < 16; ++kn) {
      float4 b4 = *(const float4*)&bb[kn*4096 + lg*4];
      s[kn][0] = fmaf(s[kn][0], SCALE2_, b4.x);
      s[kn][1] = fmaf(s[kn][1], SCALE2_, b4.y);
      s[kn][2] = fmaf(s[kn][2], SCALE2_, b4.z);
      s[kn][3] = fmaf(s[kn][3], SCALE2_, b4.w);
      mx = fmaxf(mx, fmaxf(fmaxf(s[kn][0], s[kn][1]), fmaxf(s[kn][2], s[kn][3])));
    }
    mx = fmaxf(mx, __shfl_xor(mx, 16));
    mx = fmaxf(mx, __shfl_xor(mx, 32));
    // exp2 + sum + P store (row stride 512B, XOR-swizzled bits 4..6)
    float l = 0.f;
    #pragma unroll
    for (int kn = 0; kn < 16; ++kn) {
      float p0 = __builtin_amdgcn_exp2f(s[kn][0] - mx);
      float p1 = __builtin_amdgcn_exp2f(s[kn][1] - mx);
      float p2 = __builtin_amdgcn_exp2f(s[kn][2] - mx);
      float p3 = __builtin_amdgcn_exp2f(s[kn][3] - mx);
      l += (p0 + p1) + (p2 + p3);
      uint2 pk;
      pk.x = (uint)f2bf(p0) | ((uint)f2bf(p1) << 16);
      pk.y = (uint)f2bf(p2) | ((uint)f2bf(p3) << 16);
      uint off = ((uint)lc << 9) + ((uint)kn << 5) + ((uint)lg << 3);
      off ^= (uint)(lc & 7) << 4;
      *(uint2*)(Pw + off) = pk;
    }
    l += __shfl_xor(l, 16);
    l += __shfl_xor(l, 32);
    // O^T = V^T P^T
    v4f a0 = (v4f){0.f,0.f,0.f,0.f}, a1 = (v4f){0.f,0.f,0.f,0.f};
    #pragma unroll
    for (int kc = 0; kc < 8; ++kc) {
      uint off = ((uint)lc << 9) + ((uint)kc << 6) + ((uint)lg << 4);
      off ^= (uint)(lc & 7) << 4;
      v8s pf = *(const v8s*)(Pw + off);
      v8s v0 = *(const v8s*)&Vt[lc][kc*32 + lg*8];
      v8s v1 = *(const v8s*)&Vt[16 + lc][kc*32 + lg*8];
      a0 = __builtin_amdgcn_mfma_f32_16x16x32_bf16(v0, pf, a0, 0, 0, 0);
      a1 = __builtin_amdgcn_mfma_f32_16x16x32_bf16(v1, pf, a1, 0, 0, 0);
    }
    // normalize + write to m-layout attn-out
    float inv = 1.0f / l;
    size_t ob = ((size_t)qrow*256 + j)*256 + h*32;
    #pragma unroll
    for (int i = 0; i < 2; ++i) {
      uint w0 = (uint)f2bf(a0[2*i]*inv) | ((uint)f2bf(a0[2*i+1]*inv) << 16);
      uint w1 = (uint)f2bf(a1[2*i]*inv) | ((uint)f2bf(a1[2*i+1]*inv) << 16);
      *(uint*)&ao[ob + lg*4 + 2*i]      = w0;
      *(uint*)&ao[ob + 16 + lg*4 + 2*i] = w1;
    }
  }
}

extern "C" void kernel_launch(void* const* d_in, const int* in_sizes, int n_in,
                              void* d_out, int out_size, void* d_ws, size_t ws_size,
                              hipStream_t stream) {
  const float* pair_repr = (const float*)d_in[0];
  const float* pair_bias = (const float*)d_in[1];
  const float* Wq = (const float*)d_in[2];
  const float* bq = (const float*)d_in[3];
  const float* Wk = (const float*)d_in[4];
  const float* bk = (const float*)d_in[5];
  const float* Wv = (const float*)d_in[6];
  const float* bv = (const float*)d_in[7];
  const float* Wo = (const float*)d_in[8];
  const float* bo = (const float*)d_in[9];
  const float* W1 = (const float*)d_in[10];
  const float* b1 = (const float*)d_in[11];
  const float* W2 = (const float*)d_in[12];
  const float* b2 = (const float*)d_in[13];
  const float* g1 = (const float*)d_in[14];
  const float* be1= (const float*)d_in[15];
  const float* g2 = (const float*)d_in[16];
  const float* be2= (const float*)d_in[17];
  const int* mask = (const int*)d_in[18];
  float* out = (float*)d_out;

  char* wsb = (char*)d_ws;
  // region A @0 (32MB): xb (LN1 out) -> ao (attn out)
  ushort* xb = (ushort*)wsb;
  ushort* ao = (ushort*)wsb;
  // region B @32MB (32MB): q_t -> y (LN2 out)
  ushort* qt = (ushort*)(wsb + 33554432);
  ushort* yb = qt;
  // region C @64MB (64MB): k_t(@64MB) + v_t(@96MB) -> hb (FF hidden)
  ushort* kt = (ushort*)(wsb + 67108864);
  ushort* vt = (ushort*)(wsb + 100663296);
  ushort* hb = kt;
  // region D @128MB (~4MB): weights + biases + bMt2
  char* d0 = wsb + 134217728;
  ushort* Wqkvb = (ushort*)d0;                 // 393216 B
  ushort* Wob   = (ushort*)(d0 + 393216);      // 131072 B
  ushort* W1b   = (ushort*)(d0 + 524288);      // 262144 B
  ushort* W2b   = (ushort*)(d0 + 786432);      // 262144 B
  float*  bqkv  = (float*)(d0 + 1048576);      // 3072 B
  float*  bMt2  = (float*)(d0 + 1052672);      // 2 MB

  // 0. prep
  prep_k<<<dim3(641), 256, 0, stream>>>(Wq, Wk, Wv, Wo, W1, W2, bq, bk, bv,
                                        pair_bias, mask, Wqkvb, Wob, W1b, W2b, bqkv, bMt2);
  // 1. x = LN1(pair_repr) -> xb
  ln_k<<<dim3(M_/4), 256, 0, stream>>>(pair_repr, g1, be1, xb);
  // 2. qkv projection -> head-major qt/kt/vt
  gemm3<true,false,false,true><<<dim3(3072), 256, 0, stream>>>(
      xb, Wqkvb, bqkv, nullptr, qt, 768, C_, C_, 0, 6);
  // 3. attention -> ao (region A; xb dead)
  attn4<<<dim3(L_*H_), 256, 0, stream>>>(qt, kt, vt, bMt2, ao);
  // 4. pr = ao@Wo.T + bo + pair_repr -> d_out (fp32)
  gemm3<false,false,true,false><<<dim3(1024), 256, 0, stream>>>(
      ao, Wob, bo, pair_repr, out, C_, C_, C_, C_, 2);
  // 5. y = LN2(pr) -> yb (region B; qt dead)
  ln_k<<<dim3(M_/4), 256, 0, stream>>>(out, g2, be2, yb);
  // 6. h = relu(y@W1.T + b1) -> hb (region C; kt/vt dead)
  gemm3<true,true,false,false><<<dim3(2048), 256, 0, stream>>>(
      yb, W1b, b1, nullptr, hb, F_, C_, C_, F_, 4);
  // 7. out = pr + h@W2.T + b2 -> d_out
  gemm3<false,false,true,false><<<dim3(1024), 256, 0, stream>>>(
      hb, W2b, b2, out, out, C_, F_, F_, C_, 2);
}

// Round 8
// 269.817 us; speedup vs baseline: 5.1021x; 1.2298x over previous
//
#include <hip/hip_runtime.h>

#define L_ 256
#define C_ 256
#define H_ 8
#define D_ 32
#define F_ 512
#define M_ (L_*L_)   // 65536 rows
#define SCALE2_ 0.2550348564624926f   // (1/sqrt(32)) * log2(e)
#define LOG2E_  1.4426950408889634f

typedef __attribute__((ext_vector_type(8))) short v8s;    // 8 bf16 = 16B
typedef __attribute__((ext_vector_type(4))) float v4f;    // 16x16 MFMA acc
typedef __attribute__((ext_vector_type(16))) float v16f;  // 32x32 MFMA acc
#define Z16 (v16f){0,0,0,0,0,0,0,0,0,0,0,0,0,0,0,0}

__device__ __forceinline__ ushort f2bf(float f) {
  union { float f; unsigned u; } v; v.f = f;
  unsigned r = v.u + 0x7FFFu + ((v.u >> 16) & 1u);   // RNE
  return (ushort)(r >> 16);
}

__device__ __forceinline__ void gload16(const void* g, void* l) {
  __builtin_amdgcn_global_load_lds(
      (const __attribute__((address_space(1))) void*)g,
      (__attribute__((address_space(3))) void*)l, 16, 0, 0);
}

// half-exchange: a' = [a.lo | b.lo], b' = [a.hi | b.hi]
__device__ __forceinline__ void pl32swap(uint &a, uint &b) {
  asm volatile("v_permlane32_swap_b32 %0, %1" : "+v"(a), "+v"(b));
}

// ---------------- prep: weights -> bf16, bias retile for 32x32 path ----------
// vec4 sections: Wqkv 49152 | Wo 16384 | W1 32768 | W2 32768 | bM4 131072 | bqkv 192
__global__ __launch_bounds__(256) void prep_k(
    const float* __restrict__ Wq, const float* __restrict__ Wk,
    const float* __restrict__ Wv, const float* __restrict__ Wo,
    const float* __restrict__ W1, const float* __restrict__ W2,
    const float* __restrict__ bq, const float* __restrict__ bk,
    const float* __restrict__ bv,
    const float* __restrict__ bias, const int* __restrict__ mask,
    ushort* __restrict__ Wqkvb, ushort* __restrict__ Wob,
    ushort* __restrict__ W1b, ushort* __restrict__ W2b,
    float* __restrict__ bqkv, float* __restrict__ bM4) {
  int idx = blockIdx.x * 256 + threadIdx.x;
  if (idx < 49152) {                             // Wqkv: 768x256
    int e = idx * 4; int n = e >> 8; int k = e & 255;
    const float* src = n < 256 ? &Wq[n*256 + k]
                     : n < 512 ? &Wk[(n-256)*256 + k]
                               : &Wv[(n-512)*256 + k];
    float4 f = *(const float4*)src;
    ushort4 o = { f2bf(f.x), f2bf(f.y), f2bf(f.z), f2bf(f.w) };
    *(ushort4*)&Wqkvb[e] = o;
  } else if (idx < 65536) {                      // Wo: 256x256
    int e = (idx - 49152) * 4;
    float4 f = *(const float4*)&Wo[e];
    ushort4 o = { f2bf(f.x), f2bf(f.y), f2bf(f.z), f2bf(f.w) };
    *(ushort4*)&Wob[e] = o;
  } else if (idx < 98304) {                      // W1: 512x256
    int e = (idx - 65536) * 4;
    float4 f = *(const float4*)&W1[e];
    ushort4 o = { f2bf(f.x), f2bf(f.y), f2bf(f.z), f2bf(f.w) };
    *(ushort4*)&W1b[e] = o;
  } else if (idx < 131072) {                     // W2: 256x512
    int e = (idx - 98304) * 4;
    float4 f = *(const float4*)&W2[e];
    ushort4 o = { f2bf(f.x), f2bf(f.y), f2bf(f.z), f2bf(f.w) };
    *(ushort4*)&W2b[e] = o;
  } else if (idx < 262144) {                     // bM4[h][qb][c][h5][r4][q32][j]
    int eb = idx - 131072;
    int q32 = eb & 31, r4 = (eb >> 5) & 3, h5 = (eb >> 7) & 1;
    int c = (eb >> 8) & 7, qb = (eb >> 11) & 7, h = eb >> 14;
    int q = qb*32 + q32;
    int keyb = 32*c + 8*r4 + 4*h5;
    float4 b4 = *(const float4*)&bias[((size_t)(h*256 + q))*256 + keyb];
    int4   m4 = *(const int4*)&mask[(size_t)q*256 + keyb];
    float4 o;
    o.x = m4.x ? b4.x * LOG2E_ : -1e30f;
    o.y = m4.y ? b4.y * LOG2E_ : -1e30f;
    o.z = m4.z ? b4.z * LOG2E_ : -1e30f;
    o.w = m4.w ? b4.w * LOG2E_ : -1e30f;
    *(float4*)&bM4[(size_t)eb*4] = o;
  } else if (idx < 262336) {                     // bqkv: 768
    int e = (idx - 262144) * 4;
    const float* src = e < 256 ? &bq[e] : e < 512 ? &bk[e-256] : &bv[e-512];
    *(float4*)&bqkv[e] = *(const float4*)src;
  }
}

// ---------------- LayerNorm over last dim (C=256), one wave per row ----------
__global__ __launch_bounds__(256) void ln_k(const float* __restrict__ in,
    const float* __restrict__ g, const float* __restrict__ b,
    ushort* __restrict__ out) {
  int wid = threadIdx.x >> 6, lane = threadIdx.x & 63;
  size_t row = (size_t)blockIdx.x * 4 + wid;
  const float* x = in + row * C_;
  float4 v = *(const float4*)&x[lane*4];
  float s  = v.x + v.y + v.z + v.w;
  float s2 = v.x*v.x + v.y*v.y + v.z*v.z + v.w*v.w;
  #pragma unroll
  for (int off = 1; off < 64; off <<= 1) {
    s  += __shfl_xor(s,  off);
    s2 += __shfl_xor(s2, off);
  }
  float mean = s * (1.0f/C_);
  float var  = s2 * (1.0f/C_) - mean*mean;
  float inv  = rsqrtf(var + 1e-5f);
  float4 gg = *(const float4*)&g[lane*4];
  float4 bb = *(const float4*)&b[lane*4];
  ushort4 o;
  o.x = f2bf((v.x-mean)*inv*gg.x + bb.x);
  o.y = f2bf((v.y-mean)*inv*gg.y + bb.y);
  o.z = f2bf((v.z-mean)*inv*gg.z + bb.z);
  o.w = f2bf((v.w-mean)*inv*gg.w + bb.w);
  *(ushort4*)&out[row*C_ + lane*4] = o;
}

// ---------------- bf16 MFMA NT GEMM, global_load_lds staging -----------------
template<bool OUTBF16, bool RELU, bool ADD, bool QKV>
__global__ __launch_bounds__(256) void gemm3(
    const ushort* __restrict__ A, const ushort* __restrict__ W,
    const float* __restrict__ bias, const float* __restrict__ R,
    void* __restrict__ Optr, int N, int K, int lda, int ldo, int nby) {
  __shared__ __align__(16) ushort As[128][32];   // linear dest (m97 pattern)
  __shared__ __align__(16) ushort Bs[128][32];
  int f = blockIdx.x;
  int sw = (f & 7) * (gridDim.x >> 3) + (f >> 3);   // XCD-bijective (grid%8==0)
  const int bm = (sw / nby) * 128;
  const int bn = (sw % nby) * 128;
  const int t  = threadIdx.x;
  const int lane = t & 63, w = t >> 6;
  const int wm = (w >> 1) * 64, wn = (w & 1) * 64;
  const int lg = lane >> 4, lc = lane & 15;
  const int sr = t >> 2, sc = (t & 3) * 8;

  char* ldsA0 = (char*)As + w*1024;
  char* ldsA1 = (char*)As + 4096 + w*1024;
  char* ldsB0 = (char*)Bs + w*1024;
  char* ldsB1 = (char*)Bs + 4096 + w*1024;

  v4f acc[4][4];
  #pragma unroll
  for (int i = 0; i < 4; ++i)
    #pragma unroll
    for (int jj = 0; jj < 4; ++jj) acc[i][jj] = (v4f){0.f,0.f,0.f,0.f};

  for (int k0 = 0; k0 < K; k0 += 32) {
    gload16(&A[(size_t)(bm + sr)*lda + k0 + sc],       ldsA0);
    gload16(&A[(size_t)(bm + 64 + sr)*lda + k0 + sc],  ldsA1);
    gload16(&W[(size_t)(bn + sr)*K + k0 + sc],         ldsB0);
    gload16(&W[(size_t)(bn + 64 + sr)*K + k0 + sc],    ldsB1);
    __syncthreads();
    v8s af[4], bf_[4];
    #pragma unroll
    for (int mi = 0; mi < 4; ++mi)
      af[mi] = *(const v8s*)&As[wm + mi*16 + lc][lg*8];
    #pragma unroll
    for (int ni = 0; ni < 4; ++ni)
      bf_[ni] = *(const v8s*)&Bs[wn + ni*16 + lc][lg*8];
    #pragma unroll
    for (int mi = 0; mi < 4; ++mi)
      #pragma unroll
      for (int ni = 0; ni < 4; ++ni)
        acc[mi][ni] = __builtin_amdgcn_mfma_f32_16x16x32_bf16(af[mi], bf_[ni], acc[mi][ni], 0, 0, 0);
    __syncthreads();
  }
  #pragma unroll
  for (int mi = 0; mi < 4; ++mi) {
    int mrow = bm + wm + mi*16 + lg*4;
    #pragma unroll
    for (int ni = 0; ni < 4; ++ni) {
      int ncol = bn + wn + ni*16 + lc;
      float bv = bias[ncol];
      #pragma unroll
      for (int r = 0; r < 4; ++r) {
        float o = acc[mi][ni][r] + bv;
        if (RELU) o = fmaxf(o, 0.f);
        if (QKV) {
          int m = mrow + r, i = m >> 8, jj = m & 255;
          int c = ncol & 255, proj = ncol >> 8;
          int hh = c >> 5, dd = c & 31;
          size_t idx = (size_t)proj*16777216 + (((size_t)hh*256 + jj)*256 + i)*32 + dd;
          ((ushort*)Optr)[idx] = f2bf(o);
        } else {
          size_t idx = (size_t)(mrow + r) * ldo + ncol;
          if (ADD) o += R[idx];
          if (OUTBF16) ((ushort*)Optr)[idx] = f2bf(o);
          else         ((float*)Optr)[idx]  = o;
        }
      }
    }
  }
}

// ---------------- attention per (j,h): 32x32 MFMA, zero-LDS softmax ----------
// qt/kt/vt: [h][j][i][d] bf16. bM4: [h][qb][c][h5][r4][q32][4]. ao: [i*L+j][h*32+d].
__global__ __launch_bounds__(256, 4) void attn5(
    const ushort* __restrict__ qt, const ushort* __restrict__ kt,
    const ushort* __restrict__ vt, const float* __restrict__ bM4,
    ushort* __restrict__ ao) {
  __shared__ __align__(16) ushort Vt[32][264];    // [d][key]
  const int j = blockIdx.x & 255, h = blockIdx.x >> 8;
  const int t = threadIdx.x, w = t >> 6, lane = t & 63;
  const int l5 = lane & 31, h5 = lane >> 5;
  const size_t base = ((size_t)(h*256 + j)) * 8192;

  // stage V transposed (thread = 4 keys x 8 d)
  {
    const ushort* vsrc = vt + base;
    int k4 = (t & 63) * 4, sd = (t >> 6) * 8;
    v8s v0 = *(const v8s*)&vsrc[(k4+0)*32 + sd];
    v8s v1 = *(const v8s*)&vsrc[(k4+1)*32 + sd];
    v8s v2 = *(const v8s*)&vsrc[(k4+2)*32 + sd];
    v8s v3 = *(const v8s*)&vsrc[(k4+3)*32 + sd];
    #pragma unroll
    for (int u = 0; u < 8; ++u) {
      ushort4 q4 = { (ushort)v0[u], (ushort)v1[u], (ushort)v2[u], (ushort)v3[u] };
      *(ushort4*)&Vt[sd+u][k4] = q4;
    }
  }
  __syncthreads();   // only barrier

  const ushort* ksrc = kt + base;
  const ushort* qsrc = qt + base;

  #pragma unroll 1
  for (int qi = 0; qi < 2; ++qi) {
    const int qb = w*2 + qi;
    v8s qf0 = *(const v8s*)&qsrc[(qb*32 + l5)*32 + h5*8];
    v8s qf1 = *(const v8s*)&qsrc[(qb*32 + l5)*32 + 16 + h5*8];
    const float* bqb = bM4 + (size_t)(h*8 + qb) * 8192;
    v16f o = Z16;
    float m = -1e30f, l = 0.f;

    #pragma unroll 2
    for (int c = 0; c < 8; ++c) {
      // S^T[key][q] for 32 keys: A=K, B=Q, accumulate over d-halves
      v8s kf0 = *(const v8s*)&ksrc[(c*32 + l5)*32 + h5*8];
      v8s kf1 = *(const v8s*)&ksrc[(c*32 + l5)*32 + 16 + h5*8];
      v16f s = __builtin_amdgcn_mfma_f32_32x32x16_bf16(kf0, qf0, Z16, 0, 0, 0);
      s = __builtin_amdgcn_mfma_f32_32x32x16_bf16(kf1, qf1, s, 0, 0, 0);
      // scale + masked bias (coalesced float4) + chunk max
      float sv[16];
      float pmax = -1e30f;
      #pragma unroll
      for (int r4 = 0; r4 < 4; ++r4) {
        float4 b4 = *(const float4*)&bqb[((c*2 + h5)*4 + r4)*128 + l5*4];
        sv[r4*4+0] = fmaf(s[r4*4+0], SCALE2_, b4.x);
        sv[r4*4+1] = fmaf(s[r4*4+1], SCALE2_, b4.y);
        sv[r4*4+2] = fmaf(s[r4*4+2], SCALE2_, b4.z);
        sv[r4*4+3] = fmaf(s[r4*4+3], SCALE2_, b4.w);
        pmax = fmaxf(pmax, fmaxf(fmaxf(sv[r4*4+0], sv[r4*4+1]), fmaxf(sv[r4*4+2], sv[r4*4+3])));
      }
      pmax = fmaxf(pmax, __shfl_xor(pmax, 32));
      float mnew = fmaxf(m, pmax);
      float corr = __builtin_amdgcn_exp2f(m - mnew);   // first chunk: exp2(-inf)=0
      m = mnew;
      l *= corr;
      #pragma unroll
      for (int r = 0; r < 16; ++r) o[r] *= corr;
      // exp + sum + pack
      float ls = 0.f;
      uint pk[8];
      #pragma unroll
      for (int i2 = 0; i2 < 8; ++i2) {
        float p0 = __builtin_amdgcn_exp2f(sv[2*i2]   - m);
        float p1 = __builtin_amdgcn_exp2f(sv[2*i2+1] - m);
        ls += p0 + p1;
        pk[i2] = (uint)f2bf(p0) | ((uint)f2bf(p1) << 16);
      }
      l += ls;
      // B-frags via half-exchange: keys 0-15 from pk[0..3], 16-31 from pk[4..7]
      uint w0 = pk[0], w2 = pk[2]; pl32swap(w0, w2);
      uint w1 = pk[1], w3 = pk[3]; pl32swap(w1, w3);
      uint w4 = pk[4], w6 = pk[6]; pl32swap(w4, w6);
      uint w5 = pk[5], w7 = pk[7]; pl32swap(w5, w7);
      uint4 B1 = {w0, w1, w2, w3};
      uint4 B2 = {w4, w5, w6, w7};
      // O^T += V^T P : A = V^T rows d, k = keys
      v8s vA1 = *(const v8s*)&Vt[l5][c*32 + h5*8];
      v8s vA2 = *(const v8s*)&Vt[l5][c*32 + 16 + h5*8];
      o = __builtin_amdgcn_mfma_f32_32x32x16_bf16(vA1, *(v8s*)&B1, o, 0, 0, 0);
      o = __builtin_amdgcn_mfma_f32_32x32x16_bf16(vA2, *(v8s*)&B2, o, 0, 0, 0);
    }
    // normalize (combine l across halves) + write
    float lt = l + __shfl_xor(l, 32);
    float inv = 1.0f / lt;
    size_t ob = ((size_t)(qb*32 + l5)*256 + j)*256 + h*32;
    #pragma unroll
    for (int r4 = 0; r4 < 4; ++r4) {
      uint lo = (uint)f2bf(o[4*r4+0]*inv) | ((uint)f2bf(o[4*r4+1]*inv) << 16);
      uint hi = (uint)f2bf(o[4*r4+2]*inv) | ((uint)f2bf(o[4*r4+3]*inv) << 16);
      uint2 pr; pr.x = lo; pr.y = hi;
      *(uint2*)&ao[ob + 8*r4 + 4*h5] = pr;   // d = 8*r4 + 4*h5 + 0..3
    }
  }
}

extern "C" void kernel_launch(void* const* d_in, const int* in_sizes, int n_in,
                              void* d_out, int out_size, void* d_ws, size_t ws_size,
                              hipStream_t stream) {
  const float* pair_repr = (const float*)d_in[0];
  const float* pair_bias = (const float*)d_in[1];
  const float* Wq = (const float*)d_in[2];
  const float* bq = (const float*)d_in[3];
  const float* Wk = (const float*)d_in[4];
  const float* bk = (const float*)d_in[5];
  const float* Wv = (const float*)d_in[6];
  const float* bv = (const float*)d_in[7];
  const float* Wo = (const float*)d_in[8];
  const float* bo = (const float*)d_in[9];
  const float* W1 = (const float*)d_in[10];
  const float* b1 = (const float*)d_in[11];
  const float* W2 = (const float*)d_in[12];
  const float* b2 = (const float*)d_in[13];
  const float* g1 = (const float*)d_in[14];
  const float* be1= (const float*)d_in[15];
  const float* g2 = (const float*)d_in[16];
  const float* be2= (const float*)d_in[17];
  const int* mask = (const int*)d_in[18];
  float* out = (float*)d_out;

  char* wsb = (char*)d_ws;
  // region A @0 (32MB): xb (LN1 out) -> ao (attn out)
  ushort* xb = (ushort*)wsb;
  ushort* ao = (ushort*)wsb;
  // region B @32MB (32MB): q_t -> y (LN2 out)
  ushort* qt = (ushort*)(wsb + 33554432);
  ushort* yb = qt;
  // region C @64MB (64MB): k_t(@64MB) + v_t(@96MB) -> hb (FF hidden)
  ushort* kt = (ushort*)(wsb + 67108864);
  ushort* vt = (ushort*)(wsb + 100663296);
  ushort* hb = kt;
  // region D @128MB (~4MB): weights + biases + bM4
  char* d0 = wsb + 134217728;
  ushort* Wqkvb = (ushort*)d0;                 // 393216 B
  ushort* Wob   = (ushort*)(d0 + 393216);      // 131072 B
  ushort* W1b   = (ushort*)(d0 + 524288);      // 262144 B
  ushort* W2b   = (ushort*)(d0 + 786432);      // 262144 B
  float*  bqkv  = (float*)(d0 + 1048576);      // 3072 B
  float*  bM4   = (float*)(d0 + 1052672);      // 2 MB

  // 0. prep
  prep_k<<<dim3(1025), 256, 0, stream>>>(Wq, Wk, Wv, Wo, W1, W2, bq, bk, bv,
                                         pair_bias, mask, Wqkvb, Wob, W1b, W2b, bqkv, bM4);
  // 1. x = LN1(pair_repr) -> xb
  ln_k<<<dim3(M_/4), 256, 0, stream>>>(pair_repr, g1, be1, xb);
  // 2. qkv projection -> head-major qt/kt/vt
  gemm3<true,false,false,true><<<dim3(3072), 256, 0, stream>>>(
      xb, Wqkvb, bqkv, nullptr, qt, 768, C_, C_, 0, 6);
  // 3. attention -> ao (region A; xb dead)
  attn5<<<dim3(L_*H_), 256, 0, stream>>>(qt, kt, vt, bM4, ao);
  // 4. pr = ao@Wo.T + bo + pair_repr -> d_out (fp32)
  gemm3<false,false,true,false><<<dim3(1024), 256, 0, stream>>>(
      ao, Wob, bo, pair_repr, out, C_, C_, C_, C_, 2);
  // 5. y = LN2(pr) -> yb (region B; qt dead)
  ln_k<<<dim3(M_/4), 256, 0, stream>>>(out, g2, be2, yb);
  // 6. h = relu(y@W1.T + b1) -> hb (region C; kt/vt dead)
  gemm3<true,true,false,false><<<dim3(2048), 256, 0, stream>>>(
      yb, W1b, b1, nullptr, hb, F_, C_, C_, F_, 4);
  // 7. out = pr + h@W2.T + b2 -> d_out
  gemm3<false,false,true,false><<<dim3(1024), 256, 0, stream>>>(
      hb, W2b, b2, out, out, C_, F_, F_, C_, 2);
}

// Round 9
// 261.129 us; speedup vs baseline: 5.2718x; 1.0333x over previous
//
#include <hip/hip_runtime.h>

#define L_ 256
#define C_ 256
#define H_ 8
#define D_ 32
#define F_ 512
#define M_ (L_*L_)   // 65536 rows
#define SCALE2_ 0.2550348564624926f   // (1/sqrt(32)) * log2(e)
#define LOG2E_  1.4426950408889634f

typedef __attribute__((ext_vector_type(8))) short v8s;    // 8 bf16 = 16B
typedef __attribute__((ext_vector_type(4))) float v4f;    // 16x16 MFMA acc
typedef __attribute__((ext_vector_type(16))) float v16f;  // 32x32 MFMA acc
#define Z16 (v16f){0,0,0,0,0,0,0,0,0,0,0,0,0,0,0,0}

__device__ __forceinline__ ushort f2bf(float f) {
  union { float f; unsigned u; } v; v.f = f;
  unsigned r = v.u + 0x7FFFu + ((v.u >> 16) & 1u);   // RNE
  return (ushort)(r >> 16);
}

__device__ __forceinline__ void gload16(const void* g, void* l) {
  __builtin_amdgcn_global_load_lds(
      (const __attribute__((address_space(1))) void*)g,
      (__attribute__((address_space(3))) void*)l, 16, 0, 0);
}

// half-exchange: a' = [a.lo | b.lo], b' = [a.hi | b.hi]
__device__ __forceinline__ void pl32swap(uint &a, uint &b) {
  asm volatile("v_permlane32_swap_b32 %0, %1" : "+v"(a), "+v"(b));
}

// ---------------- prep: weights -> bf16, bias retile for 32x32 path ----------
__global__ __launch_bounds__(256) void prep_k(
    const float* __restrict__ Wq, const float* __restrict__ Wk,
    const float* __restrict__ Wv, const float* __restrict__ Wo,
    const float* __restrict__ W1, const float* __restrict__ W2,
    const float* __restrict__ bq, const float* __restrict__ bk,
    const float* __restrict__ bv,
    const float* __restrict__ bias, const int* __restrict__ mask,
    ushort* __restrict__ Wqkvb, ushort* __restrict__ Wob,
    ushort* __restrict__ W1b, ushort* __restrict__ W2b,
    float* __restrict__ bqkv, float* __restrict__ bM4) {
  int idx = blockIdx.x * 256 + threadIdx.x;
  if (idx < 49152) {                             // Wqkv: 768x256
    int e = idx * 4; int n = e >> 8; int k = e & 255;
    const float* src = n < 256 ? &Wq[n*256 + k]
                     : n < 512 ? &Wk[(n-256)*256 + k]
                               : &Wv[(n-512)*256 + k];
    float4 f = *(const float4*)src;
    ushort4 o = { f2bf(f.x), f2bf(f.y), f2bf(f.z), f2bf(f.w) };
    *(ushort4*)&Wqkvb[e] = o;
  } else if (idx < 65536) {                      // Wo: 256x256
    int e = (idx - 49152) * 4;
    float4 f = *(const float4*)&Wo[e];
    ushort4 o = { f2bf(f.x), f2bf(f.y), f2bf(f.z), f2bf(f.w) };
    *(ushort4*)&Wob[e] = o;
  } else if (idx < 98304) {                      // W1: 512x256
    int e = (idx - 65536) * 4;
    float4 f = *(const float4*)&W1[e];
    ushort4 o = { f2bf(f.x), f2bf(f.y), f2bf(f.z), f2bf(f.w) };
    *(ushort4*)&W1b[e] = o;
  } else if (idx < 131072) {                     // W2: 256x512
    int e = (idx - 98304) * 4;
    float4 f = *(const float4*)&W2[e];
    ushort4 o = { f2bf(f.x), f2bf(f.y), f2bf(f.z), f2bf(f.w) };
    *(ushort4*)&W2b[e] = o;
  } else if (idx < 262144) {                     // bM4[h][qb][c][h5][r4][q32][j]
    int eb = idx - 131072;
    int q32 = eb & 31, r4 = (eb >> 5) & 3, h5 = (eb >> 7) & 1;
    int c = (eb >> 8) & 7, qb = (eb >> 11) & 7, h = eb >> 14;
    int q = qb*32 + q32;
    int keyb = 32*c + 8*r4 + 4*h5;
    float4 b4 = *(const float4*)&bias[((size_t)(h*256 + q))*256 + keyb];
    int4   m4 = *(const int4*)&mask[(size_t)q*256 + keyb];
    float4 o;
    o.x = m4.x ? b4.x * LOG2E_ : -1e30f;
    o.y = m4.y ? b4.y * LOG2E_ : -1e30f;
    o.z = m4.z ? b4.z * LOG2E_ : -1e30f;
    o.w = m4.w ? b4.w * LOG2E_ : -1e30f;
    *(float4*)&bM4[(size_t)eb*4] = o;
  } else if (idx < 262336) {                     // bqkv: 768
    int e = (idx - 262144) * 4;
    const float* src = e < 256 ? &bq[e] : e < 512 ? &bk[e-256] : &bv[e-512];
    *(float4*)&bqkv[e] = *(const float4*)src;
  }
}

// ---------------- LayerNorm; TR=true writes j-major rows ---------------------
template<bool TR>
__global__ __launch_bounds__(256) void ln_k(const float* __restrict__ in,
    const float* __restrict__ g, const float* __restrict__ b,
    ushort* __restrict__ out) {
  int wid = threadIdx.x >> 6, lane = threadIdx.x & 63;
  size_t row = (size_t)blockIdx.x * 4 + wid;
  const float* x = in + row * C_;
  float4 v = *(const float4*)&x[lane*4];
  float s  = v.x + v.y + v.z + v.w;
  float s2 = v.x*v.x + v.y*v.y + v.z*v.z + v.w*v.w;
  #pragma unroll
  for (int off = 1; off < 64; off <<= 1) {
    s  += __shfl_xor(s,  off);
    s2 += __shfl_xor(s2, off);
  }
  float mean = s * (1.0f/C_);
  float var  = s2 * (1.0f/C_) - mean*mean;
  float inv  = rsqrtf(var + 1e-5f);
  float4 gg = *(const float4*)&g[lane*4];
  float4 bb = *(const float4*)&b[lane*4];
  ushort4 o;
  o.x = f2bf((v.x-mean)*inv*gg.x + bb.x);
  o.y = f2bf((v.y-mean)*inv*gg.y + bb.y);
  o.z = f2bf((v.z-mean)*inv*gg.z + bb.z);
  o.w = f2bf((v.w-mean)*inv*gg.w + bb.w);
  size_t orow = TR ? ((row & 255) * 256 + (row >> 8)) : row;
  *(ushort4*)&out[orow*C_ + lane*4] = o;
}

// ---------------- bf16 MFMA NT GEMM: BK=64, XOR-swizzled LDS -----------------
// QKV: A is j-major (row = j*256+i); scatter to [proj][h][j][i][d] (8KB runs).
template<bool OUTBF16, bool RELU, bool ADD, bool QKV>
__global__ __launch_bounds__(256) void gemm4(
    const ushort* __restrict__ A, const ushort* __restrict__ W,
    const float* __restrict__ bias, const float* __restrict__ R,
    void* __restrict__ Optr, int N, int K, int lda, int ldo, int nby) {
  __shared__ __align__(16) ushort As[128][64];   // 16KB, chunk-swizzled
  __shared__ __align__(16) ushort Bs[128][64];
  int f = blockIdx.x;
  int sw = (f & 7) * (gridDim.x >> 3) + (f >> 3);   // XCD-bijective (grid%8==0)
  const int bm = (sw / nby) * 128;
  const int bn = (sw % nby) * 128;
  const int t  = threadIdx.x;
  const int lane = t & 63, w = t >> 6;
  const int wm = (w >> 1) * 64, wn = (w & 1) * 64;
  const int lg = lane >> 4, lc = lane & 15;
  const int srow0 = t >> 3;          // 0..31
  const int scc   = t & 7;           // 16B chunk index

  v4f acc[4][4];
  #pragma unroll
  for (int i = 0; i < 4; ++i)
    #pragma unroll
    for (int jj = 0; jj < 4; ++jj) acc[i][jj] = (v4f){0.f,0.f,0.f,0.f};

  for (int k0 = 0; k0 < K; k0 += 64) {
    // stage: LDS[row][cc] <- global chunk (cc ^ (row&7))  [involution]
    #pragma unroll
    for (int s = 0; s < 4; ++s) {
      int row = s*32 + srow0;
      int gc  = (scc ^ (row & 7)) * 8;
      gload16(&A[(size_t)(bm + row)*lda + k0 + gc], (char*)As + s*4096 + t*16);
      gload16(&W[(size_t)(bn + row)*K  + k0 + gc], (char*)Bs + s*4096 + t*16);
    }
    __syncthreads();
    #pragma unroll
    for (int kh = 0; kh < 2; ++kh) {
      v8s af[4], bf_[4];
      #pragma unroll
      for (int mi = 0; mi < 4; ++mi) {
        int row = wm + mi*16 + lc;
        int cd  = ((kh*4 + lg) ^ (row & 7)) * 16;
        af[mi] = *(const v8s*)((const char*)As + row*128 + cd);
      }
      #pragma unroll
      for (int ni = 0; ni < 4; ++ni) {
        int row = wn + ni*16 + lc;
        int cd  = ((kh*4 + lg) ^ (row & 7)) * 16;
        bf_[ni] = *(const v8s*)((const char*)Bs + row*128 + cd);
      }
      #pragma unroll
      for (int mi = 0; mi < 4; ++mi)
        #pragma unroll
        for (int ni = 0; ni < 4; ++ni)
          acc[mi][ni] = __builtin_amdgcn_mfma_f32_16x16x32_bf16(af[mi], bf_[ni], acc[mi][ni], 0, 0, 0);
    }
    __syncthreads();
  }
  #pragma unroll
  for (int mi = 0; mi < 4; ++mi) {
    int mrow = bm + wm + mi*16 + lg*4;
    #pragma unroll
    for (int ni = 0; ni < 4; ++ni) {
      int ncol = bn + wn + ni*16 + lc;
      float bv = bias[ncol];
      #pragma unroll
      for (int r = 0; r < 4; ++r) {
        float o = acc[mi][ni][r] + bv;
        if (RELU) o = fmaxf(o, 0.f);
        if (QKV) {
          int m = mrow + r, jj = m >> 8, i = m & 255;   // j-major A rows
          int c = ncol & 255, proj = ncol >> 8;
          int hh = c >> 5, dd = c & 31;
          size_t idx = (size_t)proj*16777216 + (((size_t)hh*256 + jj)*256 + i)*32 + dd;
          ((ushort*)Optr)[idx] = f2bf(o);
        } else {
          size_t idx = (size_t)(mrow + r) * ldo + ncol;
          if (ADD) o += R[idx];
          if (OUTBF16) ((ushort*)Optr)[idx] = f2bf(o);
          else         ((float*)Optr)[idx]  = o;
        }
      }
    }
  }
}

// ---------------- attention per (j,h): 32x32 MFMA, zero-LDS softmax ----------
__global__ __launch_bounds__(256, 4) void attn5(
    const ushort* __restrict__ qt, const ushort* __restrict__ kt,
    const ushort* __restrict__ vt, const float* __restrict__ bM4,
    ushort* __restrict__ ao) {
  __shared__ __align__(16) ushort Vt[32][264];    // [d][key]
  const int j = blockIdx.x & 255, h = blockIdx.x >> 8;
  const int t = threadIdx.x, w = t >> 6, lane = t & 63;
  const int l5 = lane & 31, h5 = lane >> 5;
  const size_t base = ((size_t)(h*256 + j)) * 8192;

  {
    const ushort* vsrc = vt + base;
    int k4 = (t & 63) * 4, sd = (t >> 6) * 8;
    v8s v0 = *(const v8s*)&vsrc[(k4+0)*32 + sd];
    v8s v1 = *(const v8s*)&vsrc[(k4+1)*32 + sd];
    v8s v2 = *(const v8s*)&vsrc[(k4+2)*32 + sd];
    v8s v3 = *(const v8s*)&vsrc[(k4+3)*32 + sd];
    #pragma unroll
    for (int u = 0; u < 8; ++u) {
      ushort4 q4 = { (ushort)v0[u], (ushort)v1[u], (ushort)v2[u], (ushort)v3[u] };
      *(ushort4*)&Vt[sd+u][k4] = q4;
    }
  }
  __syncthreads();   // only barrier

  const ushort* ksrc = kt + base;
  const ushort* qsrc = qt + base;

  #pragma unroll 1
  for (int qi = 0; qi < 2; ++qi) {
    const int qb = w*2 + qi;
    v8s qf0 = *(const v8s*)&qsrc[(qb*32 + l5)*32 + h5*8];
    v8s qf1 = *(const v8s*)&qsrc[(qb*32 + l5)*32 + 16 + h5*8];
    const float* bqb = bM4 + (size_t)(h*8 + qb) * 8192;
    v16f o = Z16;
    float m = -1e30f, l = 0.f;

    #pragma unroll 2
    for (int c = 0; c < 8; ++c) {
      v8s kf0 = *(const v8s*)&ksrc[(c*32 + l5)*32 + h5*8];
      v8s kf1 = *(const v8s*)&ksrc[(c*32 + l5)*32 + 16 + h5*8];
      v16f s = __builtin_amdgcn_mfma_f32_32x32x16_bf16(kf0, qf0, Z16, 0, 0, 0);
      s = __builtin_amdgcn_mfma_f32_32x32x16_bf16(kf1, qf1, s, 0, 0, 0);
      float sv[16];
      float pmax = -1e30f;
      #pragma unroll
      for (int r4 = 0; r4 < 4; ++r4) {
        float4 b4 = *(const float4*)&bqb[((c*2 + h5)*4 + r4)*128 + l5*4];
        sv[r4*4+0] = fmaf(s[r4*4+0], SCALE2_, b4.x);
        sv[r4*4+1] = fmaf(s[r4*4+1], SCALE2_, b4.y);
        sv[r4*4+2] = fmaf(s[r4*4+2], SCALE2_, b4.z);
        sv[r4*4+3] = fmaf(s[r4*4+3], SCALE2_, b4.w);
        pmax = fmaxf(pmax, fmaxf(fmaxf(sv[r4*4+0], sv[r4*4+1]), fmaxf(sv[r4*4+2], sv[r4*4+3])));
      }
      pmax = fmaxf(pmax, __shfl_xor(pmax, 32));
      float mnew = fmaxf(m, pmax);
      float corr = __builtin_amdgcn_exp2f(m - mnew);
      m = mnew;
      l *= corr;
      #pragma unroll
      for (int r = 0; r < 16; ++r) o[r] *= corr;
      float ls = 0.f;
      uint pk[8];
      #pragma unroll
      for (int i2 = 0; i2 < 8; ++i2) {
        float p0 = __builtin_amdgcn_exp2f(sv[2*i2]   - m);
        float p1 = __builtin_amdgcn_exp2f(sv[2*i2+1] - m);
        ls += p0 + p1;
        pk[i2] = (uint)f2bf(p0) | ((uint)f2bf(p1) << 16);
      }
      l += ls;
      uint w0 = pk[0], w2 = pk[2]; pl32swap(w0, w2);
      uint w1 = pk[1], w3 = pk[3]; pl32swap(w1, w3);
      uint w4 = pk[4], w6 = pk[6]; pl32swap(w4, w6);
      uint w5 = pk[5], w7 = pk[7]; pl32swap(w5, w7);
      uint4 B1 = {w0, w1, w2, w3};
      uint4 B2 = {w4, w5, w6, w7};
      v8s vA1 = *(const v8s*)&Vt[l5][c*32 + h5*8];
      v8s vA2 = *(const v8s*)&Vt[l5][c*32 + 16 + h5*8];
      o = __builtin_amdgcn_mfma_f32_32x32x16_bf16(vA1, *(v8s*)&B1, o, 0, 0, 0);
      o = __builtin_amdgcn_mfma_f32_32x32x16_bf16(vA2, *(v8s*)&B2, o, 0, 0, 0);
    }
    float lt = l + __shfl_xor(l, 32);
    float inv = 1.0f / lt;
    size_t ob = ((size_t)(qb*32 + l5)*256 + j)*256 + h*32;
    #pragma unroll
    for (int r4 = 0; r4 < 4; ++r4) {
      uint lo = (uint)f2bf(o[4*r4+0]*inv) | ((uint)f2bf(o[4*r4+1]*inv) << 16);
      uint hi = (uint)f2bf(o[4*r4+2]*inv) | ((uint)f2bf(o[4*r4+3]*inv) << 16);
      uint2 pr; pr.x = lo; pr.y = hi;
      *(uint2*)&ao[ob + 8*r4 + 4*h5] = pr;
    }
  }
}

extern "C" void kernel_launch(void* const* d_in, const int* in_sizes, int n_in,
                              void* d_out, int out_size, void* d_ws, size_t ws_size,
                              hipStream_t stream) {
  const float* pair_repr = (const float*)d_in[0];
  const float* pair_bias = (const float*)d_in[1];
  const float* Wq = (const float*)d_in[2];
  const float* bq = (const float*)d_in[3];
  const float* Wk = (const float*)d_in[4];
  const float* bk = (const float*)d_in[5];
  const float* Wv = (const float*)d_in[6];
  const float* bv = (const float*)d_in[7];
  const float* Wo = (const float*)d_in[8];
  const float* bo = (const float*)d_in[9];
  const float* W1 = (const float*)d_in[10];
  const float* b1 = (const float*)d_in[11];
  const float* W2 = (const float*)d_in[12];
  const float* b2 = (const float*)d_in[13];
  const float* g1 = (const float*)d_in[14];
  const float* be1= (const float*)d_in[15];
  const float* g2 = (const float*)d_in[16];
  const float* be2= (const float*)d_in[17];
  const int* mask = (const int*)d_in[18];
  float* out = (float*)d_out;

  char* wsb = (char*)d_ws;
  ushort* xb = (ushort*)wsb;                    // region A: LN1 out (j-major) -> ao
  ushort* ao = (ushort*)wsb;
  ushort* qt = (ushort*)(wsb + 33554432);       // region B: q_t -> yb
  ushort* yb = qt;
  ushort* kt = (ushort*)(wsb + 67108864);       // region C: k_t, v_t -> hb
  ushort* vt = (ushort*)(wsb + 100663296);
  ushort* hb = kt;
  char* d0 = wsb + 134217728;                   // region D: weights/bias
  ushort* Wqkvb = (ushort*)d0;
  ushort* Wob   = (ushort*)(d0 + 393216);
  ushort* W1b   = (ushort*)(d0 + 524288);
  ushort* W2b   = (ushort*)(d0 + 786432);
  float*  bqkv  = (float*)(d0 + 1048576);
  float*  bM4   = (float*)(d0 + 1052672);

  // 0. prep
  prep_k<<<dim3(1025), 256, 0, stream>>>(Wq, Wk, Wv, Wo, W1, W2, bq, bk, bv,
                                         pair_bias, mask, Wqkvb, Wob, W1b, W2b, bqkv, bM4);
  // 1. x = LN1(pair_repr) -> xb (j-major rows)
  ln_k<true><<<dim3(M_/4), 256, 0, stream>>>(pair_repr, g1, be1, xb);
  // 2. qkv projection -> head-major qt/kt/vt (contiguous 8KB runs per (h,j))
  gemm4<true,false,false,true><<<dim3(3072), 256, 0, stream>>>(
      xb, Wqkvb, bqkv, nullptr, (void*)qt, 768, C_, C_, 0, 6);
  // 3. attention -> ao (region A; xb dead)
  attn5<<<dim3(L_*H_), 256, 0, stream>>>(qt, kt, vt, bM4, ao);
  // 4. pr = ao@Wo.T + bo + pair_repr -> d_out (fp32)
  gemm4<false,false,true,false><<<dim3(1024), 256, 0, stream>>>(
      ao, Wob, bo, pair_repr, out, C_, C_, C_, C_, 2);
  // 5. y = LN2(pr) -> yb (i-major; region B, qt dead)
  ln_k<false><<<dim3(M_/4), 256, 0, stream>>>(out, g2, be2, yb);
  // 6. h = relu(y@W1.T + b1) -> hb (region C; kt/vt dead)
  gemm4<true,true,false,false><<<dim3(2048), 256, 0, stream>>>(
      yb, W1b, b1, nullptr, (void*)hb, F_, C_, C_, F_, 4);
  // 7. out = pr + h@W2.T + b2 -> d_out
  gemm4<false,false,true,false><<<dim3(1024), 256, 0, stream>>>(
      hb, W2b, b2, out, out, C_, F_, F_, C_, 2);
}